// Round 12
// baseline (3062.868 us; speedup 1.0000x reference)
//
#include <hip/hip_runtime.h>
#include <stdint.h>

// ---------------- problem constants ----------------
#define NN     1600
#define NBEAT  200
#define FINW   299
#define HSTR   300      // padded row stride for h
#define SECW   43
#define EDG    12
#define C3     129      // 3*43 projected width
#define CM     128      // main columns (129th handled separately)
#define DEG_CAP 256     // per-destination adjacency bucket (mean 77, max~112)
#define GBLK   1024     // fused g-loop grid (4 blocks/CU, 2 waves each -> co-resident)

__device__ __forceinline__ float sigm(float x){ return 1.0f/(1.0f+__expf(-x)); }
__device__ __forceinline__ float tanh_(float x){ return 2.0f/(1.0f+__expf(-2.0f*x)) - 1.0f; }

// ---------------- workspace layout (4-byte words) ----------------
constexpr size_t OFF_H    = 0;                                   // 1600*300
constexpr size_t OFF_WA3  = OFF_H    + (size_t)NN*HSTR;          // 12*299*128
constexpr size_t OFF_WA3X = OFF_WA3  + (size_t)EDG*FINW*CM;      // 12*299
constexpr size_t OFF_B3   = OFF_WA3X + (size_t)EDG*FINW;         // 132
constexpr size_t OFF_MST  = OFF_B3   + 132;                      // 12*1600*128
constexpr size_t OFF_MSTX = OFF_MST  + (size_t)EDG*NN*CM;        // 12*1600
constexpr size_t OFF_M3   = OFF_MSTX + (size_t)EDG*NN;           // 12*1600*128
constexpr size_t OFF_M3X  = OFF_M3   + (size_t)EDG*NN*CM;        // 12*1600
constexpr size_t OFF_CUR  = OFF_M3X  + (size_t)EDG*NN;           // 1600 ints (degree counters)
constexpr size_t OFF_BAR  = OFF_CUR  + NN;                       // 128 ints (device barrier)
constexpr size_t OFF_ADJR = OFF_BAR  + 128;                      // 1600*256 ints
constexpr size_t OFF_XW   = OFF_ADJR + (size_t)NN*DEG_CAP;       // 2*200*128
constexpr size_t OFF_RNN0 = OFF_XW   + (size_t)2*NBEAT*128;      // 200*64
constexpr size_t OFF_RNN1 = OFF_RNN0 + (size_t)NBEAT*64;         // 200*64

// ---------------- device-wide barrier (two-level, sharded, generation-based) ----------------
// bar[0]=generation, bar[1]=master, bar[2..65]=64 shard counters; GBLK blocks, 16/shard.
__device__ __forceinline__ void gbar(int* bar){
  __syncthreads();   // drains block's vmcnt -> all block stores at L2
  if (threadIdx.x==0){
    __threadfence(); // release: write-back L2 to device scope
    int s = blockIdx.x & 63;
    int g = __hip_atomic_load(&bar[0], __ATOMIC_RELAXED, __HIP_MEMORY_SCOPE_AGENT);
    int v = __hip_atomic_fetch_add(&bar[2+s], 1, __ATOMIC_ACQ_REL, __HIP_MEMORY_SCOPE_AGENT);
    if (v == (GBLK/64)-1){
      __hip_atomic_store(&bar[2+s], 0, __ATOMIC_RELAXED, __HIP_MEMORY_SCOPE_AGENT);
      int w = __hip_atomic_fetch_add(&bar[1], 1, __ATOMIC_ACQ_REL, __HIP_MEMORY_SCOPE_AGENT);
      if (w == 63){
        __hip_atomic_store(&bar[1], 0, __ATOMIC_RELAXED, __HIP_MEMORY_SCOPE_AGENT);
        __hip_atomic_fetch_add(&bar[0], 1, __ATOMIC_RELEASE, __HIP_MEMORY_SCOPE_AGENT);
      }
    }
    while (__hip_atomic_load(&bar[0], __ATOMIC_ACQUIRE, __HIP_MEMORY_SCOPE_AGENT) == g)
      __builtin_amdgcn_s_sleep(2);
    __threadfence(); // acquire: invalidate stale L1/L2 lines
  }
  __syncthreads();
}

// ---------------- setup kernels ----------------
__global__ void k_wa3(const float* wa, const float* ba,
                      const float* wz, const float* wr, const float* wh, float* ws){
  int b = blockIdx.x;
  bool isB = (b == EDG*FINW);
  int e = b/FINW, d = b - e*FINW;
  __shared__ float lrow[FINW];
  const float* row = isB ? ba : (wa + ((size_t)e*FINW + d)*FINW);
  for (int s=threadIdx.x; s<FINW; s+=128) lrow[s]=row[s];
  __syncthreads();
  for (int c=threadIdx.x; c<C3; c+=128){
    const float* Wp; int cc;
    if (c<43){Wp=wz; cc=c;} else if (c<86){Wp=wr; cc=c-43;} else {Wp=wh; cc=c-86;}
    float acc=0.f;
    for (int s=0;s<FINW;s++) acc += lrow[s]*Wp[s*43+cc];
    if (isB) ws[OFF_B3 + c] = acc;
    else if (c<CM) ws[OFF_WA3 + ((size_t)e*FINW+d)*CM + c] = acc;
    else           ws[OFF_WA3X + (size_t)e*FINW + d]       = acc;
  }
}

__global__ void k_init(const float* note, const float* pv, const float* w_style, const float* b_style,
                       const float* w1, const float* b1,
                       const float* w2, const float* b2, float* ws, float* dout){
  int i = blockIdx.x, t = threadIdx.x;   // 128 threads
  __shared__ float lnote[128];
  __shared__ float lh1[64];
  __shared__ float lo[11];
  __shared__ float lperf[64];
  lnote[t]=note[i*128+t];
  if (t>=64){
    int u=t-64;
    float acc=b_style[u];
    for (int k=0;k<16;k++) acc += pv[k]*w_style[k*64+u];
    lperf[u]=fmaxf(acc,0.f);
  }
  __syncthreads();
  if (t<64){
    float acc=b1[t];
    for (int k=0;k<128;k++) acc += lnote[k]*w1[k*64+t];
    lh1[t]=fmaxf(acc,0.f);
  }
  __syncthreads();
  if (t<11){
    float acc=b2[t];
    for (int s=0;s<64;s++) acc += lh1[s]*w2[s*11+t];
    lo[t]=acc;
    dout[17600 + i*11 + t] = acc;
  }
  __syncthreads();
  for (int c=t;c<FINW;c+=128){
    float v;
    if (c<128)      v=lnote[c];
    else if (c<192) v=lperf[c-128];
    else if (c<256) v=0.f;
    else if (c<267) v=lo[c-256];
    else            v=0.f;
    ws[OFF_H + (size_t)i*HSTR + c]=v;
  }
}

// ---------------- sparse edge extraction: single scan, fixed-width buckets ----------------
__global__ void k_adj(const float* edges, float* ws){
  int* cur  = (int*)(ws + OFF_CUR);
  int* adjr = (int*)(ws + OFF_ADJR);
  const uint4* p = (const uint4*)edges;
  const unsigned int nvec = 7680000u;   // 12*1600*1600/4
  for (unsigned int v = blockIdx.x*blockDim.x + threadIdx.x; v<nvec; v += gridDim.x*blockDim.x){
    uint4 w = p[v];
    if ((w.x|w.y|w.z|w.w)==0u) continue;
    unsigned int base = v*4u;
    unsigned int arr[4]={w.x,w.y,w.z,w.w};
    #pragma unroll
    for (int q=0;q<4;q++){
      if (arr[q]){
        unsigned int idx=base+q;
        unsigned int j=idx%1600u;
        int slot=atomicAdd(&cur[j],1);
        if (slot<DEG_CAP) adjr[j*DEG_CAP + slot]=(int)(idx/1600u);  // row = e*1600+i
      }
    }
  }
}

// ---------------- static message part + M3(h0) (once per seq-iter) ----------------
__global__ void k_mstat(float* ws){
  int e = blockIdx.y; int i0 = blockIdx.x*8;
  int t = threadIdx.x;
  __shared__ float lh[8][256];
  __shared__ float lh2[8][44];
  const float* h = ws + OFF_H;
  for (int x=t; x<512; x+=64){
    int r = x>>6, dq = x&63;
    ((float4*)&lh[r][0])[dq] = ((const float4*)(h + (size_t)(i0+r)*HSTR))[dq];
  }
  for (int x=t; x<88; x+=64){
    int r = x/11, dq = x-r*11;
    ((float4*)&lh2[r][0])[dq] = ((const float4*)(h + (size_t)(i0+r)*HSTR + 256))[dq];
  }
  __syncthreads();
  const float* wm = ws + OFF_WA3 + (size_t)e*FINW*CM;
  int c0 = 2*t;
  float acc[8][2];
  #pragma unroll
  for (int r=0;r<8;r++){acc[r][0]=0.f;acc[r][1]=0.f;}
  for (int d=0; d<256; d+=4){
    float4 hv[8];
    #pragma unroll
    for (int r=0;r<8;r++) hv[r] = *(const float4*)&lh[r][d];
    #pragma unroll
    for (int dd=0;dd<4;dd++){
      float2 w = *(const float2*)(wm + (size_t)(d+dd)*CM + c0);
      #pragma unroll
      for (int r=0;r<8;r++){
        float hvv = ((const float*)&hv[r])[dd];
        acc[r][0] += hvv*w.x; acc[r][1] += hvv*w.y;
      }
    }
  }
  float* mst = ws + OFF_MST + ((size_t)e*NN + i0)*CM;
  #pragma unroll
  for (int r=0;r<8;r++) *(float2*)(mst + (size_t)r*CM + c0) = make_float2(acc[r][0],acc[r][1]);
  // continue over dynamic cols 256..298 -> M3 = mst + hs@wd
  const float* wd = wm + (size_t)256*CM;
  for (int d=0; d<SECW; d++){
    float2 w = *(const float2*)(wd + (size_t)d*CM + c0);
    #pragma unroll
    for (int r=0;r<8;r++){
      float hvv = lh2[r][d];
      acc[r][0] += hvv*w.x; acc[r][1] += hvv*w.y;
    }
  }
  float* m3 = ws + OFF_M3 + ((size_t)e*NN + i0)*CM;
  #pragma unroll
  for (int r=0;r<8;r++) *(float2*)(m3 + (size_t)r*CM + c0) = make_float2(acc[r][0],acc[r][1]);
  if (t<8){
    const float* wx = ws + OFF_WA3X + (size_t)e*FINW;
    float a=0.f;
    for (int d=0; d<256; d++) a += lh[t][d]*wx[d];
    ws[OFF_MSTX + (size_t)e*NN + i0 + t] = a;
    for (int d=0; d<SECW; d++) a += lh2[t][d]*wx[256+d];
    ws[OFF_M3X + (size_t)e*NN + i0 + t] = a;
  }
}

// ---------------- fused g-loop: agg, [barrier, M3-recompute, barrier, agg] x2 ----------------
__global__ __launch_bounds__(128) void k_giter(float* ws, const float* uz, const float* ur, const float* uh){
  int t = threadIdx.x;
  int* bar = (int*)(ws + OFF_BAR);
  __shared__ float lhs8[8][44];
  __shared__ float lpre[C3];
  __shared__ float lhsj[SECW];
  __shared__ float lrh[SECW];
  __shared__ int   ladj[DEG_CAP];
  float* h = ws + OFF_H;
  const int* cur =(const int*)(ws+OFF_CUR);
  for (int g=0; g<3; g++){
    // ---- agg + GRU phase (proven k_agg_gru body, grid-strided) ----
    for (int j=blockIdx.x; j<NN; j+=GBLK){
      __syncthreads();   // protect shared reuse across j iterations
      const int* adjr=(const int*)(ws+OFF_ADJR) + (size_t)j*DEG_CAP;
      int cnt = cur[j]; if (cnt>DEG_CAP) cnt=DEG_CAP;
      for (int k=t;k<cnt;k+=128) ladj[k]=adjr[k];
      if (t<SECW) lhsj[t] = h[(size_t)j*HSTR + 256 + t];
      __syncthreads();
      const float* M3=ws+OFF_M3; const float* M3X=ws+OFF_M3X;
      float a0 = ws[OFF_B3 + t];
      float ax = (t==0)? ws[OFF_B3+128] : 0.f;
      float p1=0.f,p2=0.f,p3=0.f,p4=0.f,p5=0.f,p6=0.f,p7=0.f;
      int k=0;
      for (; k+8<=cnt; k+=8){
        int r0=ladj[k],r1=ladj[k+1],r2=ladj[k+2],r3=ladj[k+3];
        int r4=ladj[k+4],r5=ladj[k+5],r6=ladj[k+6],r7=ladj[k+7];
        a0 += M3[(size_t)r0*CM+t];
        p1 += M3[(size_t)r1*CM+t];
        p2 += M3[(size_t)r2*CM+t];
        p3 += M3[(size_t)r3*CM+t];
        p4 += M3[(size_t)r4*CM+t];
        p5 += M3[(size_t)r5*CM+t];
        p6 += M3[(size_t)r6*CM+t];
        p7 += M3[(size_t)r7*CM+t];
        if (t==0) ax += ((M3X[r0]+M3X[r1])+(M3X[r2]+M3X[r3]))
                      + ((M3X[r4]+M3X[r5])+(M3X[r6]+M3X[r7]));
      }
      for (; k<cnt; k++){ int r=ladj[k]; a0+=M3[(size_t)r*CM+t]; if(t==0) ax+=M3X[r]; }
      a0 += ((p1+p2)+(p3+p4)) + ((p5+p6)+p7);
      lpre[t]=a0; if (t==0) lpre[128]=ax;
      __syncthreads();
      float z=0.f;
      if (t<SECW){
        float az=lpre[t], ar=lpre[43+t];
        for (int d=0;d<SECW;d++){ float hv=lhsj[d]; az+=hv*uz[d*43+t]; ar+=hv*ur[d*43+t]; }
        z=sigm(az);
        float r=sigm(ar);
        lrh[t]=r*lhsj[t];
      }
      __syncthreads();
      if (t<SECW){
        float ah=lpre[86+t];
        for (int d=0;d<SECW;d++) ah += lrh[d]*uh[d*43+t];
        float cand=tanh_(ah);
        h[(size_t)j*HSTR+256+t] = (1.f-z)*lhsj[t] + z*cand;
      }
    }
    if (g==2) break;
    gbar(bar);
    // ---- M3 recompute phase (proven k_m3dyn body, 128-thr/1-col, grid-strided) ----
    for (int T=blockIdx.x; T<2400; T+=GBLK){
      int e = T/200, i0 = (T - e*200)*8;
      __syncthreads();
      for (int x=t; x<8*SECW; x+=128){ int r=x/SECW, d=x-r*SECW; lhs8[r][d]=h[(size_t)(i0+r)*HSTR+256+d]; }
      __syncthreads();
      const float* wd  = ws + OFF_WA3 + ((size_t)e*FINW+256)*CM;
      const float* mst = ws + OFF_MST + ((size_t)e*NN+i0)*CM;
      float acc[8];
      #pragma unroll
      for (int r=0;r<8;r++) acc[r]=mst[(size_t)r*CM+t];
      for (int d=0; d<SECW; d++){
        float w=wd[(size_t)d*CM+t];
        #pragma unroll
        for (int r=0;r<8;r++) acc[r] += lhs8[r][d]*w;
      }
      float* m3 = ws + OFF_M3 + ((size_t)e*NN+i0)*CM;
      #pragma unroll
      for (int r=0;r<8;r++) m3[(size_t)r*CM+t]=acc[r];
      if (t<8){
        float a = ws[OFF_MSTX + (size_t)e*NN+i0+t];
        const float* wx = ws + OFF_WA3X + (size_t)e*FINW + 256;
        for (int d=0;d<SECW;d++) a += lhs8[t][d]*wx[d];
        ws[OFF_M3X + (size_t)e*NN+i0+t]=a;
      }
    }
    gbar(bar);
  }
}

// ---------------- beat attention + layer-0 LSTM input projection (fused) ----------------
__global__ void k_attn_xw(float* ws, const float* mw, const float* mb, const float* mc,
                          const float* bw, const float* bb, const float* bc,
                          const float* res,
                          const float* w0f, const float* bia0f,
                          const float* w0b, const float* bia0b, float* xw){
  int b=blockIdx.x, t=threadIdx.x;  // 128 threads
  float* h=ws+OFF_H;
  __shared__ float sm[8][8];
  __shared__ float wgt[8][8];
  __shared__ float sb[8];
  __shared__ float wb_[8];
  __shared__ float lb[52];
  int n=t>>3, hh=t&7;
  if (t<64){
    const float* mrow = h + (size_t)(b*8+n)*HSTR + 267;
    float sim=0.f;
    for (int d=0;d<4;d++){
      int c=hh*4+d;
      float acc=mb[c];
      for (int k=0;k<32;k++) acc += mrow[k]*mw[k*32+c];
      sim += tanh_(acc)*mc[c];
    }
    sm[n][hh]=sim;
  }
  if (t<8){
    const float* irow = h + (size_t)(b*8+t)*HSTR + 256;
    float sim=0.f;
    for (int d=0;d<11;d++){
      float acc=bb[d];
      for (int k=0;k<11;k++) acc += irow[k]*bw[k*11+d];
      sim += tanh_(acc)*bc[d];
    }
    sb[t]=sim;
  }
  __syncthreads();
  if (t<64){
    float m=-1e30f;
    for (int q=0;q<8;q++) m=fmaxf(m, sm[q][hh]);
    float Z=0.f;
    for (int q=0;q<8;q++) Z+=__expf(sm[q][hh]-m);
    wgt[n][hh]=__expf(sm[n][hh]-m)/Z;
  }
  if (t<8){
    float m=-1e30f;
    for (int q=0;q<8;q++) m=fmaxf(m, sb[q]);
    float Z=0.f;
    for (int q=0;q<8;q++) Z+=__expf(sb[q]-m);
    wb_[t]=__expf(sb[t]-m)/Z;
  }
  __syncthreads();
  if (t<32){
    int hh2=t>>2;
    float acc=0.f;
    for (int q=0;q<8;q++) acc += wgt[q][hh2]* h[(size_t)(b*8+q)*HSTR + 267 + t];
    lb[11+t]=acc;
  }
  if (t<11){
    float acc=0.f;
    for (int q=0;q<8;q++) acc += wb_[q]* h[(size_t)(b*8+q)*HSTR + 256 + t];
    lb[t]=acc;
  }
  if (t<8) lb[43+t]=res[b*8+t];
  __syncthreads();
  float acc0=bia0f[t], acc1=bia0b[t];
  for (int k=0;k<51;k++){
    float v=lb[k];
    acc0 += v*w0f[t*51+k];
    acc1 += v*w0b[t*51+k];
  }
  xw[((size_t)0*NBEAT + b)*128 + t]=acc0;
  xw[((size_t)1*NBEAT + b)*128 + t]=acc1;
}

// ---------------- LSTM layer-1 input projection ----------------
__global__ void k_xw(const float* inp, int din, const float* wf, const float* bf_,
                     const float* wb, const float* bb_, float* xw){
  int bid=blockIdx.x; int tt=bid>>1, dir=bid&1;
  const float* w = dir? wb:wf; const float* bia = dir? bb_:bf_;
  __shared__ float rowl[64];
  int t=threadIdx.x;   // 128 threads
  if (t<din) rowl[t]=inp[(size_t)tt*din+t];
  __syncthreads();
  float acc=bia[t];
  for (int k=0;k<din;k++) acc += rowl[k]*w[t*din+k];
  xw[((size_t)dir*NBEAT + tt)*128 + t]=acc;
}

// R5/R10 scan verbatim (PASSED @87us): one wave per direction; lane l<32: i_l,g_l; l>=32: f,o;
// c in high lanes. h via LDS (no inner wave_barriers!); x staged in 8-step LDS chunks.
#define CH 8
__global__ __launch_bounds__(64,1) void k_scan(const float* xw, const float* whh_f,
                                               const float* whh_b, float* out){
  int dir = blockIdx.x;
  int l = threadIdx.x;
  const float* whh = dir ? whh_b : whh_f;
  float4 rA[8], rB[8];
  #pragma unroll
  for (int q=0;q<8;q++){
    rA[q] = *(const float4*)&whh[l*32 + q*4];
    rB[q] = *(const float4*)&whh[(l+64)*32 + q*4];
  }
  __shared__ __align__(16) float xb[2][CH*128];
  __shared__ __align__(16) float lds_h[32];
  if (l<32) lds_h[l]=0.f;
  const float* x = xw + (size_t)dir*NBEAT*128;
  int half = l>>5, q4 = l&31;
  int stp = dir ? -1 : 1;
  float4 st[4];
  #pragma unroll
  for (int r=0;r<4;r++){
    int s = 2*r + half;
    int ti = dir ? (NBEAT-1-s) : s;
    st[r] = ((const float4*)&x[ti*128])[q4];
  }
  #pragma unroll
  for (int r=0;r<4;r++){ int u=2*r+half; ((float4*)&xb[0][u*128])[q4]=st[r]; }
  __builtin_amdgcn_wave_barrier();
  float creg = 0.f;
  int tt = dir ? NBEAT-1 : 0;
  for (int c=0;c<NBEAT/CH;c++){
    int buf = c&1;
    if (c+1 < NBEAT/CH){       // issue next chunk's global loads now (consumed at chunk end)
      #pragma unroll
      for (int r=0;r<4;r++){
        int s = (c+1)*CH + 2*r + half;
        int ti = dir ? (NBEAT-1-s) : s;
        st[r] = ((const float4*)&x[ti*128])[q4];
      }
    }
    #pragma unroll
    for (int u=0;u<CH;u++){
      float cxA = xb[buf][u*128 + l];
      float cxB = xb[buf][u*128 + 64 + l];
      float4 hv[8];
      #pragma unroll
      for (int q=0;q<8;q++) hv[q] = *(const float4*)&lds_h[q*4];   // broadcast reads
      float a[8], bq[8];
      #pragma unroll
      for (int q=0;q<8;q++){
        float4 h4=hv[q], wa=rA[q], wb=rB[q];
        a[q]  = h4.x*wa.x + h4.y*wa.y + h4.z*wa.z + h4.w*wa.w;
        bq[q] = h4.x*wb.x + h4.y*wb.y + h4.z*wb.z + h4.w*wb.w;
      }
      float accA = cxA + ((a[0]+a[1])+(a[2]+a[3])) + ((a[4]+a[5])+(a[6]+a[7]));
      float accB = cxB + ((bq[0]+bq[1])+(bq[2]+bq[3])) + ((bq[4]+bq[5])+(bq[6]+bq[7]));
      float pA  = sigm(accA);      // sigm(i) low lanes, sigm(f) high lanes
      float pBt = tanh_(accB);     // tanh(g) low lanes
      float pBs = sigm(accB);      // sigm(o) high lanes
      float prod = pA * pBt;
      float prodIn = __shfl(prod, l & 31, 64);
      creg = pA*creg + prodIn;     // c update (high lanes valid)
      float hnew = pBs * tanh_(creg);
      if (l>=32){
        lds_h[l&31] = hnew;        // program order + LDS aliasing keep write->read ordered in-wave
        out[(size_t)tt*64 + dir*32 + (l&31)] = hnew;
      }
      tt += stp;
    }
    if (c+1 < NBEAT/CH){
      #pragma unroll
      for (int r=0;r<4;r++){ int u=2*r+half; ((float4*)&xb[1-buf][u*128])[q4]=st[r]; }
      __builtin_amdgcn_wave_barrier();
    }
  }
}

// ---------------- fc head + final_out + h update (tempo fused) ----------------
__global__ void k_fc(float* ws, const int* bn, const float* w1, const float* b1,
                     const float* w2, const float* b2,
                     const float* wt, const float* bt, float* dout, int it){
  int i=blockIdx.x, t=threadIdx.x;   // 64 threads
  __shared__ float row[FINW];
  __shared__ float hid[32];
  __shared__ float fo[11];
  float* h=ws+OFF_H;
  int b = bn[i];
  const float* rnn = ws+OFF_RNN1;
  for (int c=t;c<FINW;c+=64){
    float v;
    if (c>=192 && c<256){ v=rnn[(size_t)b*64 + c-192]; h[(size_t)i*HSTR+c]=v; }
    else v=h[(size_t)i*HSTR+c];
    row[c]=v;
  }
  float tv = rnn[(size_t)b*64 + t]*wt[t];
  #pragma unroll
  for (int off=32; off; off>>=1) tv += __shfl_xor(tv, off, 64);
  __syncthreads();
  if (t<32){
    float acc=b1[t];
    for (int k=0;k<FINW;k++) acc += row[k]*w1[k*32+t];
    hid[t]=fmaxf(acc,0.f);
  }
  __syncthreads();
  if (t<10){
    float acc=b2[t];
    for (int m=0;m<32;m++) acc += hid[m]*w2[m*10+t];
    fo[1+t]=acc;
  }
  if (t==0) fo[0]=tv + bt[0];
  __syncthreads();
  if (t<11){
    float v=fo[t];
    h[(size_t)i*HSTR+256+t]=v;
    dout[(size_t)(2+it)*17600 + i*11 + t]=v;
    if (it==1) dout[i*11+t]=v;
  }
}

// ---------------- launcher ----------------
extern "C" void kernel_launch(void* const* d_in, const int* in_sizes, int n_in,
                              void* d_out, int out_size, void* d_ws, size_t ws_size,
                              hipStream_t stream){
  (void)in_sizes; (void)n_in; (void)out_size; (void)ws_size;
  float* ws=(float*)d_ws;
  const float* note    =(const float*)d_in[0];
  const float* pv      =(const float*)d_in[1];
  const float* res     =(const float*)d_in[2];
  const float* edges   =(const float*)d_in[3];
  const int*   bn      =(const int*)d_in[4];
  const float* w_style =(const float*)d_in[5];
  const float* b_style =(const float*)d_in[6];
  const float* w_init1 =(const float*)d_in[7];
  const float* b_init1 =(const float*)d_in[8];
  const float* w_init2 =(const float*)d_in[9];
  const float* b_init2 =(const float*)d_in[10];
  const float* gg_wa   =(const float*)d_in[11];
  const float* gg_ba   =(const float*)d_in[12];
  const float* gg_wz   =(const float*)d_in[13];
  const float* gg_wr   =(const float*)d_in[14];
  const float* gg_wh   =(const float*)d_in[15];
  const float* gg_uz   =(const float*)d_in[16];
  const float* gg_ur   =(const float*)d_in[17];
  const float* gg_uh   =(const float*)d_in[18];
  const float* abw     =(const float*)d_in[19];
  const float* abb     =(const float*)d_in[20];
  const float* abc     =(const float*)d_in[21];
  const float* amw     =(const float*)d_in[22];
  const float* amb     =(const float*)d_in[23];
  const float* amc     =(const float*)d_in[24];
  const float* wih0f   =(const float*)d_in[25];
  const float* whh0f   =(const float*)d_in[26];
  const float* b0f     =(const float*)d_in[27];
  const float* wih0b   =(const float*)d_in[28];
  const float* whh0b   =(const float*)d_in[29];
  const float* b0b     =(const float*)d_in[30];
  const float* wih1f   =(const float*)d_in[31];
  const float* whh1f   =(const float*)d_in[32];
  const float* b1f     =(const float*)d_in[33];
  const float* wih1b   =(const float*)d_in[34];
  const float* whh1b   =(const float*)d_in[35];
  const float* b1b     =(const float*)d_in[36];
  const float* w_tempo =(const float*)d_in[37];
  const float* b_tempo =(const float*)d_in[38];
  const float* w_fc1   =(const float*)d_in[39];
  const float* b_fc1   =(const float*)d_in[40];
  const float* w_fc2   =(const float*)d_in[41];
  const float* b_fc2   =(const float*)d_in[42];
  float* dout=(float*)d_out;

  hipMemsetAsync(ws+OFF_CUR, 0, (NN+128)*sizeof(int), stream);   // degree counters + barrier
  k_wa3<<<EDG*FINW+1,128,0,stream>>>(gg_wa,gg_ba,gg_wz,gg_wr,gg_wh,ws);
  k_init<<<NN,128,0,stream>>>(note,pv,w_style,b_style,w_init1,b_init1,w_init2,b_init2,ws,dout);
  k_adj<<<1920,256,0,stream>>>(edges,ws);

  for (int it=0; it<2; it++){
    k_mstat<<<dim3(200,12),64,0,stream>>>(ws);
    k_giter<<<GBLK,128,0,stream>>>(ws,gg_uz,gg_ur,gg_uh);
    k_attn_xw<<<NBEAT,128,0,stream>>>(ws,amw,amb,amc,abw,abb,abc,res,
                                      wih0f,b0f,wih0b,b0b,ws+OFF_XW);
    k_scan<<<2,64,0,stream>>>(ws+OFF_XW,whh0f,whh0b,ws+OFF_RNN0);
    k_xw<<<2*NBEAT,128,0,stream>>>(ws+OFF_RNN0,64,wih1f,b1f,wih1b,b1b,ws+OFF_XW);
    k_scan<<<2,64,0,stream>>>(ws+OFF_XW,whh1f,whh1b,ws+OFF_RNN1);
    k_fc<<<NN,64,0,stream>>>(ws,bn,w_fc1,b_fc1,w_fc2,b_fc2,w_tempo,b_tempo,dout,it);
  }
}

// Round 13
// 932.726 us; speedup vs baseline: 3.2838x; 3.2838x over previous
//
#include <hip/hip_runtime.h>
#include <stdint.h>

// ---------------- problem constants ----------------
#define NN     1600
#define NBEAT  200
#define FINW   299
#define HSTR   300      // padded row stride for h
#define SECW   43
#define EDG    12
#define C3     129      // 3*43 projected width
#define CM     128      // main columns (129th handled separately)
#define DEG_CAP 256     // per-destination adjacency bucket (mean 77, max~112)

__device__ __forceinline__ float sigm(float x){ return 1.0f/(1.0f+__expf(-x)); }
__device__ __forceinline__ float tanh_(float x){ return 2.0f/(1.0f+__expf(-2.0f*x)) - 1.0f; }

// ---------------- workspace layout (4-byte words) ----------------
constexpr size_t OFF_H    = 0;                                   // 1600*300
constexpr size_t OFF_WA3  = OFF_H    + (size_t)NN*HSTR;          // 12*299*128
constexpr size_t OFF_WA3X = OFF_WA3  + (size_t)EDG*FINW*CM;      // 12*299
constexpr size_t OFF_B3   = OFF_WA3X + (size_t)EDG*FINW;         // 132
constexpr size_t OFF_MST  = OFF_B3   + 132;                      // 12*1600*128
constexpr size_t OFF_MSTX = OFF_MST  + (size_t)EDG*NN*CM;        // 12*1600
constexpr size_t OFF_M3   = OFF_MSTX + (size_t)EDG*NN;           // 12*1600*128
constexpr size_t OFF_M3X  = OFF_M3   + (size_t)EDG*NN*CM;        // 12*1600
constexpr size_t OFF_CUR  = OFF_M3X  + (size_t)EDG*NN;           // 1600 ints (degree counters)
constexpr size_t OFF_ADJR = OFF_CUR  + NN;                       // 1600*256 ints
constexpr size_t OFF_XW   = OFF_ADJR + (size_t)NN*DEG_CAP;       // 2*200*128
constexpr size_t OFF_RNN0 = OFF_XW   + (size_t)2*NBEAT*128;      // 200*64
constexpr size_t OFF_RNN1 = OFF_RNN0 + (size_t)NBEAT*64;         // 200*64

// ---------------- setup kernels ----------------
__global__ void k_wa3(const float* wa, const float* ba,
                      const float* wz, const float* wr, const float* wh, float* ws){
  int b = blockIdx.x;
  bool isB = (b == EDG*FINW);
  int e = b/FINW, d = b - e*FINW;
  __shared__ float lrow[FINW];
  const float* row = isB ? ba : (wa + ((size_t)e*FINW + d)*FINW);
  for (int s=threadIdx.x; s<FINW; s+=128) lrow[s]=row[s];
  __syncthreads();
  for (int c=threadIdx.x; c<C3; c+=128){
    const float* Wp; int cc;
    if (c<43){Wp=wz; cc=c;} else if (c<86){Wp=wr; cc=c-43;} else {Wp=wh; cc=c-86;}
    float acc=0.f;
    for (int s=0;s<FINW;s++) acc += lrow[s]*Wp[s*43+cc];
    if (isB) ws[OFF_B3 + c] = acc;
    else if (c<CM) ws[OFF_WA3 + ((size_t)e*FINW+d)*CM + c] = acc;
    else           ws[OFF_WA3X + (size_t)e*FINW + d]       = acc;
  }
}

__global__ void k_init(const float* note, const float* pv, const float* w_style, const float* b_style,
                       const float* w1, const float* b1,
                       const float* w2, const float* b2, float* ws, float* dout){
  int i = blockIdx.x, t = threadIdx.x;   // 128 threads
  __shared__ float lnote[128];
  __shared__ float lh1[64];
  __shared__ float lo[11];
  __shared__ float lperf[64];
  lnote[t]=note[i*128+t];
  if (t>=64){
    int u=t-64;
    float acc=b_style[u];
    for (int k=0;k<16;k++) acc += pv[k]*w_style[k*64+u];
    lperf[u]=fmaxf(acc,0.f);
  }
  __syncthreads();
  if (t<64){
    float acc=b1[t];
    for (int k=0;k<128;k++) acc += lnote[k]*w1[k*64+t];
    lh1[t]=fmaxf(acc,0.f);
  }
  __syncthreads();
  if (t<11){
    float acc=b2[t];
    for (int s=0;s<64;s++) acc += lh1[s]*w2[s*11+t];
    lo[t]=acc;
    dout[17600 + i*11 + t] = acc;
  }
  __syncthreads();
  for (int c=t;c<FINW;c+=128){
    float v;
    if (c<128)      v=lnote[c];
    else if (c<192) v=lperf[c-128];
    else if (c<256) v=0.f;
    else if (c<267) v=lo[c-256];
    else            v=0.f;
    ws[OFF_H + (size_t)i*HSTR + c]=v;
  }
}

// ---------------- sparse edge extraction: single scan, fixed-width buckets ----------------
__global__ void k_adj(const float* edges, float* ws){
  int* cur  = (int*)(ws + OFF_CUR);
  int* adjr = (int*)(ws + OFF_ADJR);
  const uint4* p = (const uint4*)edges;
  const unsigned int nvec = 7680000u;   // 12*1600*1600/4
  for (unsigned int v = blockIdx.x*blockDim.x + threadIdx.x; v<nvec; v += gridDim.x*blockDim.x){
    uint4 w = p[v];
    if ((w.x|w.y|w.z|w.w)==0u) continue;
    unsigned int base = v*4u;
    unsigned int arr[4]={w.x,w.y,w.z,w.w};
    #pragma unroll
    for (int q=0;q<4;q++){
      if (arr[q]){
        unsigned int idx=base+q;
        unsigned int j=idx%1600u;
        int slot=atomicAdd(&cur[j],1);
        if (slot<DEG_CAP) adjr[j*DEG_CAP + slot]=(int)(idx/1600u);  // row = e*1600+i
      }
    }
  }
}

// ---------------- static message part + M3(h0) (once per seq-iter) ----------------
__global__ void k_mstat(float* ws){
  int e = blockIdx.y; int i0 = blockIdx.x*8;
  int t = threadIdx.x;
  __shared__ float lh[8][256];
  __shared__ float lh2[8][44];
  const float* h = ws + OFF_H;
  for (int x=t; x<512; x+=64){
    int r = x>>6, dq = x&63;
    ((float4*)&lh[r][0])[dq] = ((const float4*)(h + (size_t)(i0+r)*HSTR))[dq];
  }
  for (int x=t; x<88; x+=64){
    int r = x/11, dq = x-r*11;
    ((float4*)&lh2[r][0])[dq] = ((const float4*)(h + (size_t)(i0+r)*HSTR + 256))[dq];
  }
  __syncthreads();
  const float* wm = ws + OFF_WA3 + (size_t)e*FINW*CM;
  int c0 = 2*t;
  float acc[8][2];
  #pragma unroll
  for (int r=0;r<8;r++){acc[r][0]=0.f;acc[r][1]=0.f;}
  for (int d=0; d<256; d+=4){
    float4 hv[8];
    #pragma unroll
    for (int r=0;r<8;r++) hv[r] = *(const float4*)&lh[r][d];
    #pragma unroll
    for (int dd=0;dd<4;dd++){
      float2 w = *(const float2*)(wm + (size_t)(d+dd)*CM + c0);
      #pragma unroll
      for (int r=0;r<8;r++){
        float hvv = ((const float*)&hv[r])[dd];
        acc[r][0] += hvv*w.x; acc[r][1] += hvv*w.y;
      }
    }
  }
  float* mst = ws + OFF_MST + ((size_t)e*NN + i0)*CM;
  #pragma unroll
  for (int r=0;r<8;r++) *(float2*)(mst + (size_t)r*CM + c0) = make_float2(acc[r][0],acc[r][1]);
  // continue over dynamic cols 256..298 -> M3 = mst + hs@wd
  const float* wd = wm + (size_t)256*CM;
  for (int d=0; d<SECW; d++){
    float2 w = *(const float2*)(wd + (size_t)d*CM + c0);
    #pragma unroll
    for (int r=0;r<8;r++){
      float hvv = lh2[r][d];
      acc[r][0] += hvv*w.x; acc[r][1] += hvv*w.y;
    }
  }
  float* m3 = ws + OFF_M3 + ((size_t)e*NN + i0)*CM;
  #pragma unroll
  for (int r=0;r<8;r++) *(float2*)(m3 + (size_t)r*CM + c0) = make_float2(acc[r][0],acc[r][1]);
  if (t<8){
    const float* wx = ws + OFF_WA3X + (size_t)e*FINW;
    float a=0.f;
    for (int d=0; d<256; d++) a += lh[t][d]*wx[d];
    ws[OFF_MSTX + (size_t)e*NN + i0 + t] = a;
    for (int d=0; d<SECW; d++) a += lh2[t][d]*wx[256+d];
    ws[OFF_M3X + (size_t)e*NN + i0 + t] = a;
  }
}

// ---------------- M3 recompute (g>=1) ----------------
__global__ void k_m3dyn(float* ws){
  int e=blockIdx.y, i0=blockIdx.x*8, t=threadIdx.x;
  __shared__ float lhs[8][44];
  const float* h = ws + OFF_H;
  for (int x=t; x<8*43; x+=64){ int r=x/43, d=x-r*43; lhs[r][d]=h[(size_t)(i0+r)*HSTR+256+d]; }
  __syncthreads();
  const float* wd  = ws + OFF_WA3 + ((size_t)e*FINW+256)*CM;
  const float* mst = ws + OFF_MST + ((size_t)e*NN+i0)*CM;
  int c0=2*t;
  float acc[8][2];
  #pragma unroll
  for (int r=0;r<8;r++){ float2 m=*(const float2*)(mst+(size_t)r*CM+c0); acc[r][0]=m.x; acc[r][1]=m.y; }
  for (int d=0; d<43; d++){
    float2 w=*(const float2*)(wd + (size_t)d*CM + c0);
    #pragma unroll
    for (int r=0;r<8;r++){ float hv=lhs[r][d]; acc[r][0]+=hv*w.x; acc[r][1]+=hv*w.y; }
  }
  float* m3 = ws + OFF_M3 + ((size_t)e*NN+i0)*CM;
  #pragma unroll
  for (int r=0;r<8;r++) *(float2*)(m3+(size_t)r*CM+c0)=make_float2(acc[r][0],acc[r][1]);
  if (t<8){
    float a = ws[OFF_MSTX + (size_t)e*NN+i0+t];
    const float* wx = ws + OFF_WA3X + (size_t)e*FINW + 256;
    for (int d=0;d<43;d++) a += lhs[t][d]*wx[d];
    ws[OFF_M3X + (size_t)e*NN+i0+t]=a;
  }
}

// gather (LDS-staged adjacency + 8 independent accumulators) + GRU update
__global__ void k_agg_gru(float* ws, const float* uz, const float* ur, const float* uh){
  int j=blockIdx.x, t=threadIdx.x;   // 128 threads
  __shared__ float lpre[C3];
  __shared__ float lhs[SECW];
  __shared__ float lrh[SECW];
  __shared__ int   ladj[DEG_CAP];
  float* h = ws + OFF_H;
  const int* cur =(const int*)(ws+OFF_CUR);
  const int* adjr=(const int*)(ws+OFF_ADJR) + (size_t)j*DEG_CAP;
  int cnt = cur[j]; if (cnt>DEG_CAP) cnt=DEG_CAP;
  for (int k=t;k<cnt;k+=128) ladj[k]=adjr[k];
  if (t<SECW) lhs[t] = h[(size_t)j*HSTR + 256 + t];
  __syncthreads();
  const float* M3=ws+OFF_M3; const float* M3X=ws+OFF_M3X;
  float a0 = ws[OFF_B3 + t];
  float ax = (t==0)? ws[OFF_B3+128] : 0.f;
  float p1=0.f,p2=0.f,p3=0.f,p4=0.f,p5=0.f,p6=0.f,p7=0.f;
  int k=0;
  for (; k+8<=cnt; k+=8){
    int r0=ladj[k],r1=ladj[k+1],r2=ladj[k+2],r3=ladj[k+3];
    int r4=ladj[k+4],r5=ladj[k+5],r6=ladj[k+6],r7=ladj[k+7];
    a0 += M3[(size_t)r0*CM+t];
    p1 += M3[(size_t)r1*CM+t];
    p2 += M3[(size_t)r2*CM+t];
    p3 += M3[(size_t)r3*CM+t];
    p4 += M3[(size_t)r4*CM+t];
    p5 += M3[(size_t)r5*CM+t];
    p6 += M3[(size_t)r6*CM+t];
    p7 += M3[(size_t)r7*CM+t];
    if (t==0) ax += ((M3X[r0]+M3X[r1])+(M3X[r2]+M3X[r3]))
                  + ((M3X[r4]+M3X[r5])+(M3X[r6]+M3X[r7]));
  }
  for (; k<cnt; k++){ int r=ladj[k]; a0+=M3[(size_t)r*CM+t]; if(t==0) ax+=M3X[r]; }
  a0 += ((p1+p2)+(p3+p4)) + ((p5+p6)+p7);
  lpre[t]=a0; if (t==0) lpre[128]=ax;
  __syncthreads();
  float z=0.f;
  if (t<SECW){
    float az=lpre[t], ar=lpre[43+t];
    for (int d=0;d<SECW;d++){ float hv=lhs[d]; az+=hv*uz[d*43+t]; ar+=hv*ur[d*43+t]; }
    z=sigm(az);
    float r=sigm(ar);
    lrh[t]=r*lhs[t];
  }
  __syncthreads();
  if (t<SECW){
    float ah=lpre[86+t];
    for (int d=0;d<SECW;d++) ah += lrh[d]*uh[d*43+t];
    float cand=tanh_(ah);
    h[(size_t)j*HSTR+256+t] = (1.f-z)*lhs[t] + z*cand;
  }
}

// ---------------- beat attention + layer-0 LSTM input projection (fused) ----------------
__global__ void k_attn_xw(float* ws, const float* mw, const float* mb, const float* mc,
                          const float* bw, const float* bb, const float* bc,
                          const float* res,
                          const float* w0f, const float* bia0f,
                          const float* w0b, const float* bia0b, float* xw){
  int b=blockIdx.x, t=threadIdx.x;  // 128 threads
  float* h=ws+OFF_H;
  __shared__ float sm[8][8];
  __shared__ float wgt[8][8];
  __shared__ float sb[8];
  __shared__ float wb_[8];
  __shared__ float lb[52];
  int n=t>>3, hh=t&7;
  if (t<64){
    const float* mrow = h + (size_t)(b*8+n)*HSTR + 267;
    float sim=0.f;
    for (int d=0;d<4;d++){
      int c=hh*4+d;
      float acc=mb[c];
      for (int k=0;k<32;k++) acc += mrow[k]*mw[k*32+c];
      sim += tanh_(acc)*mc[c];
    }
    sm[n][hh]=sim;
  }
  if (t<8){
    const float* irow = h + (size_t)(b*8+t)*HSTR + 256;
    float sim=0.f;
    for (int d=0;d<11;d++){
      float acc=bb[d];
      for (int k=0;k<11;k++) acc += irow[k]*bw[k*11+d];
      sim += tanh_(acc)*bc[d];
    }
    sb[t]=sim;
  }
  __syncthreads();
  if (t<64){
    float m=-1e30f;
    for (int q=0;q<8;q++) m=fmaxf(m, sm[q][hh]);
    float Z=0.f;
    for (int q=0;q<8;q++) Z+=__expf(sm[q][hh]-m);
    wgt[n][hh]=__expf(sm[n][hh]-m)/Z;
  }
  if (t<8){
    float m=-1e30f;
    for (int q=0;q<8;q++) m=fmaxf(m, sb[q]);
    float Z=0.f;
    for (int q=0;q<8;q++) Z+=__expf(sb[q]-m);
    wb_[t]=__expf(sb[t]-m)/Z;
  }
  __syncthreads();
  if (t<32){
    int hh2=t>>2;
    float acc=0.f;
    for (int q=0;q<8;q++) acc += wgt[q][hh2]* h[(size_t)(b*8+q)*HSTR + 267 + t];
    lb[11+t]=acc;
  }
  if (t<11){
    float acc=0.f;
    for (int q=0;q<8;q++) acc += wb_[q]* h[(size_t)(b*8+q)*HSTR + 256 + t];
    lb[t]=acc;
  }
  if (t<8) lb[43+t]=res[b*8+t];
  __syncthreads();
  float acc0=bia0f[t], acc1=bia0b[t];
  for (int k=0;k<51;k++){
    float v=lb[k];
    acc0 += v*w0f[t*51+k];
    acc1 += v*w0b[t*51+k];
  }
  xw[((size_t)0*NBEAT + b)*128 + t]=acc0;
  xw[((size_t)1*NBEAT + b)*128 + t]=acc1;
}

// ---------------- LSTM layer-1 input projection ----------------
__global__ void k_xw(const float* inp, int din, const float* wf, const float* bf_,
                     const float* wb, const float* bb_, float* xw){
  int bid=blockIdx.x; int tt=bid>>1, dir=bid&1;
  const float* w = dir? wb:wf; const float* bia = dir? bb_:bf_;
  __shared__ float rowl[64];
  int t=threadIdx.x;   // 128 threads
  if (t<din) rowl[t]=inp[(size_t)tt*din+t];
  __syncthreads();
  float acc=bia[t];
  for (int k=0;k<din;k++) acc += rowl[k]*w[t*din+k];
  xw[((size_t)dir*NBEAT + tt)*128 + t]=acc;
}

// R5/R10 scan verbatim (PASSED @87us): one wave per direction; lane l<32: i_l,g_l; l>=32: f,o;
// c in high lanes. h via LDS (no inner wave_barriers!); x staged in 8-step LDS chunks.
#define CH 8
__global__ __launch_bounds__(64,1) void k_scan(const float* xw, const float* whh_f,
                                               const float* whh_b, float* out){
  int dir = blockIdx.x;
  int l = threadIdx.x;
  const float* whh = dir ? whh_b : whh_f;
  float4 rA[8], rB[8];
  #pragma unroll
  for (int q=0;q<8;q++){
    rA[q] = *(const float4*)&whh[l*32 + q*4];
    rB[q] = *(const float4*)&whh[(l+64)*32 + q*4];
  }
  __shared__ __align__(16) float xb[2][CH*128];
  __shared__ __align__(16) float lds_h[32];
  if (l<32) lds_h[l]=0.f;
  const float* x = xw + (size_t)dir*NBEAT*128;
  int half = l>>5, q4 = l&31;
  int stp = dir ? -1 : 1;
  float4 st[4];
  #pragma unroll
  for (int r=0;r<4;r++){
    int s = 2*r + half;
    int ti = dir ? (NBEAT-1-s) : s;
    st[r] = ((const float4*)&x[ti*128])[q4];
  }
  #pragma unroll
  for (int r=0;r<4;r++){ int u=2*r+half; ((float4*)&xb[0][u*128])[q4]=st[r]; }
  __builtin_amdgcn_wave_barrier();
  float creg = 0.f;
  int tt = dir ? NBEAT-1 : 0;
  for (int c=0;c<NBEAT/CH;c++){
    int buf = c&1;
    if (c+1 < NBEAT/CH){       // issue next chunk's global loads now (consumed at chunk end)
      #pragma unroll
      for (int r=0;r<4;r++){
        int s = (c+1)*CH + 2*r + half;
        int ti = dir ? (NBEAT-1-s) : s;
        st[r] = ((const float4*)&x[ti*128])[q4];
      }
    }
    #pragma unroll
    for (int u=0;u<CH;u++){
      float cxA = xb[buf][u*128 + l];
      float cxB = xb[buf][u*128 + 64 + l];
      float4 hv[8];
      #pragma unroll
      for (int q=0;q<8;q++) hv[q] = *(const float4*)&lds_h[q*4];   // broadcast reads
      float a[8], bq[8];
      #pragma unroll
      for (int q=0;q<8;q++){
        float4 h4=hv[q], wa=rA[q], wb=rB[q];
        a[q]  = h4.x*wa.x + h4.y*wa.y + h4.z*wa.z + h4.w*wa.w;
        bq[q] = h4.x*wb.x + h4.y*wb.y + h4.z*wb.z + h4.w*wb.w;
      }
      float accA = cxA + ((a[0]+a[1])+(a[2]+a[3])) + ((a[4]+a[5])+(a[6]+a[7]));
      float accB = cxB + ((bq[0]+bq[1])+(bq[2]+bq[3])) + ((bq[4]+bq[5])+(bq[6]+bq[7]));
      float pA  = sigm(accA);      // sigm(i) low lanes, sigm(f) high lanes
      float pBt = tanh_(accB);     // tanh(g) low lanes
      float pBs = sigm(accB);      // sigm(o) high lanes
      float prod = pA * pBt;
      float prodIn = __shfl(prod, l & 31, 64);
      creg = pA*creg + prodIn;     // c update (high lanes valid)
      float hnew = pBs * tanh_(creg);
      if (l>=32){
        lds_h[l&31] = hnew;        // program order + LDS aliasing keep write->read ordered in-wave
        out[(size_t)tt*64 + dir*32 + (l&31)] = hnew;
      }
      tt += stp;
    }
    if (c+1 < NBEAT/CH){
      #pragma unroll
      for (int r=0;r<4;r++){ int u=2*r+half; ((float4*)&xb[1-buf][u*128])[q4]=st[r]; }
      __builtin_amdgcn_wave_barrier();
    }
  }
}

// ---------------- fc head + final_out + h update (tempo fused) ----------------
__global__ void k_fc(float* ws, const int* bn, const float* w1, const float* b1,
                     const float* w2, const float* b2,
                     const float* wt, const float* bt, float* dout, int it){
  int i=blockIdx.x, t=threadIdx.x;   // 64 threads
  __shared__ float row[FINW];
  __shared__ float hid[32];
  __shared__ float fo[11];
  float* h=ws+OFF_H;
  int b = bn[i];
  const float* rnn = ws+OFF_RNN1;
  for (int c=t;c<FINW;c+=64){
    float v;
    if (c>=192 && c<256){ v=rnn[(size_t)b*64 + c-192]; h[(size_t)i*HSTR+c]=v; }
    else v=h[(size_t)i*HSTR+c];
    row[c]=v;
  }
  float tv = rnn[(size_t)b*64 + t]*wt[t];
  #pragma unroll
  for (int off=32; off; off>>=1) tv += __shfl_xor(tv, off, 64);
  __syncthreads();
  if (t<32){
    float acc=b1[t];
    for (int k=0;k<FINW;k++) acc += row[k]*w1[k*32+t];
    hid[t]=fmaxf(acc,0.f);
  }
  __syncthreads();
  if (t<10){
    float acc=b2[t];
    for (int m=0;m<32;m++) acc += hid[m]*w2[m*10+t];
    fo[1+t]=acc;
  }
  if (t==0) fo[0]=tv + bt[0];
  __syncthreads();
  if (t<11){
    float v=fo[t];
    h[(size_t)i*HSTR+256+t]=v;
    dout[(size_t)(2+it)*17600 + i*11 + t]=v;
    if (it==1) dout[i*11+t]=v;
  }
}

// ---------------- launcher ----------------
extern "C" void kernel_launch(void* const* d_in, const int* in_sizes, int n_in,
                              void* d_out, int out_size, void* d_ws, size_t ws_size,
                              hipStream_t stream){
  (void)in_sizes; (void)n_in; (void)out_size; (void)ws_size;
  float* ws=(float*)d_ws;
  const float* note    =(const float*)d_in[0];
  const float* pv      =(const float*)d_in[1];
  const float* res     =(const float*)d_in[2];
  const float* edges   =(const float*)d_in[3];
  const int*   bn      =(const int*)d_in[4];
  const float* w_style =(const float*)d_in[5];
  const float* b_style =(const float*)d_in[6];
  const float* w_init1 =(const float*)d_in[7];
  const float* b_init1 =(const float*)d_in[8];
  const float* w_init2 =(const float*)d_in[9];
  const float* b_init2 =(const float*)d_in[10];
  const float* gg_wa   =(const float*)d_in[11];
  const float* gg_ba   =(const float*)d_in[12];
  const float* gg_wz   =(const float*)d_in[13];
  const float* gg_wr   =(const float*)d_in[14];
  const float* gg_wh   =(const float*)d_in[15];
  const float* gg_uz   =(const float*)d_in[16];
  const float* gg_ur   =(const float*)d_in[17];
  const float* gg_uh   =(const float*)d_in[18];
  const float* abw     =(const float*)d_in[19];
  const float* abb     =(const float*)d_in[20];
  const float* abc     =(const float*)d_in[21];
  const float* amw     =(const float*)d_in[22];
  const float* amb     =(const float*)d_in[23];
  const float* amc     =(const float*)d_in[24];
  const float* wih0f   =(const float*)d_in[25];
  const float* whh0f   =(const float*)d_in[26];
  const float* b0f     =(const float*)d_in[27];
  const float* wih0b   =(const float*)d_in[28];
  const float* whh0b   =(const float*)d_in[29];
  const float* b0b     =(const float*)d_in[30];
  const float* wih1f   =(const float*)d_in[31];
  const float* whh1f   =(const float*)d_in[32];
  const float* b1f     =(const float*)d_in[33];
  const float* wih1b   =(const float*)d_in[34];
  const float* whh1b   =(const float*)d_in[35];
  const float* b1b     =(const float*)d_in[36];
  const float* w_tempo =(const float*)d_in[37];
  const float* b_tempo =(const float*)d_in[38];
  const float* w_fc1   =(const float*)d_in[39];
  const float* b_fc1   =(const float*)d_in[40];
  const float* w_fc2   =(const float*)d_in[41];
  const float* b_fc2   =(const float*)d_in[42];
  float* dout=(float*)d_out;

  hipMemsetAsync(ws+OFF_CUR, 0, NN*sizeof(int), stream);
  k_wa3<<<EDG*FINW+1,128,0,stream>>>(gg_wa,gg_ba,gg_wz,gg_wr,gg_wh,ws);
  k_init<<<NN,128,0,stream>>>(note,pv,w_style,b_style,w_init1,b_init1,w_init2,b_init2,ws,dout);
  k_adj<<<1920,256,0,stream>>>(edges,ws);

  for (int it=0; it<2; it++){
    k_mstat<<<dim3(200,12),64,0,stream>>>(ws);      // also emits M3(h0)
    k_agg_gru<<<NN,128,0,stream>>>(ws,gg_uz,gg_ur,gg_uh);          // g=0
    for (int g=1; g<3; g++){
      k_m3dyn<<<dim3(200,12),64,0,stream>>>(ws);
      k_agg_gru<<<NN,128,0,stream>>>(ws,gg_uz,gg_ur,gg_uh);
    }
    k_attn_xw<<<NBEAT,128,0,stream>>>(ws,amw,amb,amc,abw,abb,abc,res,
                                      wih0f,b0f,wih0b,b0b,ws+OFF_XW);
    k_scan<<<2,64,0,stream>>>(ws+OFF_XW,whh0f,whh0b,ws+OFF_RNN0);
    k_xw<<<2*NBEAT,128,0,stream>>>(ws+OFF_RNN0,64,wih1f,b1f,wih1b,b1b,ws+OFF_XW);
    k_scan<<<2,64,0,stream>>>(ws+OFF_XW,whh1f,whh1b,ws+OFF_RNN1);
    k_fc<<<NN,64,0,stream>>>(ws,bn,w_fc1,b_fc1,w_fc2,b_fc2,w_tempo,b_tempo,dout,it);
  }
}

// Round 14
// 928.579 us; speedup vs baseline: 3.2984x; 1.0045x over previous
//
#include <hip/hip_runtime.h>
#include <stdint.h>

// ---------------- problem constants ----------------
#define NN     1600
#define NBEAT  200
#define FINW   299
#define HSTR   300      // padded row stride for h
#define SECW   43
#define EDG    12
#define C3     129      // 3*43 projected width
#define CM     128      // main columns (129th handled separately)
#define DEG_CAP 256     // per-destination adjacency bucket (mean 77, max~112)

// fused-setup block ranges (all 128-thread blocks)
#define NB_WA3  (EDG*FINW+1)          // 3589
#define NB_INIT NN                    // 1600
#define NB_ADJ  3840                  // k_adj: 3840*128 = 491520 threads (same as 1920*256)

__device__ __forceinline__ float sigm(float x){ return 1.0f/(1.0f+__expf(-x)); }
__device__ __forceinline__ float tanh_(float x){ return 2.0f/(1.0f+__expf(-2.0f*x)) - 1.0f; }

// ---------------- workspace layout (4-byte words) ----------------
constexpr size_t OFF_H    = 0;                                   // 1600*300
constexpr size_t OFF_WA3  = OFF_H    + (size_t)NN*HSTR;          // 12*299*128
constexpr size_t OFF_WA3X = OFF_WA3  + (size_t)EDG*FINW*CM;      // 12*299
constexpr size_t OFF_B3   = OFF_WA3X + (size_t)EDG*FINW;         // 132
constexpr size_t OFF_MST  = OFF_B3   + 132;                      // 12*1600*128
constexpr size_t OFF_MSTX = OFF_MST  + (size_t)EDG*NN*CM;        // 12*1600
constexpr size_t OFF_M3   = OFF_MSTX + (size_t)EDG*NN;           // 12*1600*128
constexpr size_t OFF_M3X  = OFF_M3   + (size_t)EDG*NN*CM;        // 12*1600
constexpr size_t OFF_CUR  = OFF_M3X  + (size_t)EDG*NN;           // 1600 ints (degree counters)
constexpr size_t OFF_ADJR = OFF_CUR  + NN;                       // 1600*256 ints
constexpr size_t OFF_XW   = OFF_ADJR + (size_t)NN*DEG_CAP;       // 2*200*128
constexpr size_t OFF_RNN0 = OFF_XW   + (size_t)2*NBEAT*128;      // 200*64
constexpr size_t OFF_RNN1 = OFF_RNN0 + (size_t)NBEAT*64;         // 200*64

// ---------------- fused setup: wa3 | init | adj (independent work, one dispatch) ----------------
__global__ __launch_bounds__(128) void k_setup(
    const float* wa, const float* ba, const float* wz, const float* wr, const float* wh,
    const float* note, const float* pv, const float* w_style, const float* b_style,
    const float* w1, const float* b1, const float* w2, const float* b2,
    const float* edges, float* ws, float* dout){
  int blk = blockIdx.x;
  int t = threadIdx.x;
  if (blk < NB_WA3){
    // ---- wa3: wa3[e][d][c] = sum_s wa[e][d][s]*Wcat[s][c]; last block does b3 ----
    int b = blk;
    bool isB = (b == EDG*FINW);
    int e = b/FINW, d = b - e*FINW;
    __shared__ float lrow[FINW];
    const float* row = isB ? ba : (wa + ((size_t)e*FINW + d)*FINW);
    for (int s=t; s<FINW; s+=128) lrow[s]=row[s];
    __syncthreads();
    for (int c=t; c<C3; c+=128){
      const float* Wp; int cc;
      if (c<43){Wp=wz; cc=c;} else if (c<86){Wp=wr; cc=c-43;} else {Wp=wh; cc=c-86;}
      float acc=0.f;
      for (int s=0;s<FINW;s++) acc += lrow[s]*Wp[s*43+cc];
      if (isB) ws[OFF_B3 + c] = acc;
      else if (c<CM) ws[OFF_WA3 + ((size_t)e*FINW+d)*CM + c] = acc;
      else           ws[OFF_WA3X + (size_t)e*FINW + d]       = acc;
    }
  } else if (blk < NB_WA3 + NB_INIT){
    // ---- init: perf_z + init_out + assemble h row; writes total[0] ----
    int i = blk - NB_WA3;
    __shared__ float lnote[128];
    __shared__ float lh1[64];
    __shared__ float lo[11];
    __shared__ float lperf[64];
    lnote[t]=note[i*128+t];
    if (t>=64){
      int u=t-64;
      float acc=b_style[u];
      for (int k=0;k<16;k++) acc += pv[k]*w_style[k*64+u];
      lperf[u]=fmaxf(acc,0.f);
    }
    __syncthreads();
    if (t<64){
      float acc=b1[t];
      for (int k=0;k<128;k++) acc += lnote[k]*w1[k*64+t];
      lh1[t]=fmaxf(acc,0.f);
    }
    __syncthreads();
    if (t<11){
      float acc=b2[t];
      for (int s=0;s<64;s++) acc += lh1[s]*w2[s*11+t];
      lo[t]=acc;
      dout[17600 + i*11 + t] = acc;
    }
    __syncthreads();
    for (int c=t;c<FINW;c+=128){
      float v;
      if (c<128)      v=lnote[c];
      else if (c<192) v=lperf[c-128];
      else if (c<256) v=0.f;
      else if (c<267) v=lo[c-256];
      else            v=0.f;
      ws[OFF_H + (size_t)i*HSTR + c]=v;
    }
  } else {
    // ---- adj: sparse edge extraction into fixed-width buckets ----
    int ab = blk - NB_WA3 - NB_INIT;   // 0..NB_ADJ-1
    int* cur  = (int*)(ws + OFF_CUR);
    int* adjr = (int*)(ws + OFF_ADJR);
    const uint4* p = (const uint4*)edges;
    const unsigned int nvec = 7680000u;   // 12*1600*1600/4
    const unsigned int stride = (unsigned int)NB_ADJ*128u;
    for (unsigned int v = (unsigned int)ab*128u + t; v<nvec; v += stride){
      uint4 w = p[v];
      if ((w.x|w.y|w.z|w.w)==0u) continue;
      unsigned int base = v*4u;
      unsigned int arr[4]={w.x,w.y,w.z,w.w};
      #pragma unroll
      for (int q=0;q<4;q++){
        if (arr[q]){
          unsigned int idx=base+q;
          unsigned int j=idx%1600u;
          int slot=atomicAdd(&cur[j],1);
          if (slot<DEG_CAP) adjr[j*DEG_CAP + slot]=(int)(idx/1600u);  // row = e*1600+i
        }
      }
    }
  }
}

// ---------------- static message part + M3(h0) (once per seq-iter) ----------------
__global__ void k_mstat(float* ws){
  int e = blockIdx.y; int i0 = blockIdx.x*8;
  int t = threadIdx.x;
  __shared__ float lh[8][256];
  __shared__ float lh2[8][44];
  const float* h = ws + OFF_H;
  for (int x=t; x<512; x+=64){
    int r = x>>6, dq = x&63;
    ((float4*)&lh[r][0])[dq] = ((const float4*)(h + (size_t)(i0+r)*HSTR))[dq];
  }
  for (int x=t; x<88; x+=64){
    int r = x/11, dq = x-r*11;
    ((float4*)&lh2[r][0])[dq] = ((const float4*)(h + (size_t)(i0+r)*HSTR + 256))[dq];
  }
  __syncthreads();
  const float* wm = ws + OFF_WA3 + (size_t)e*FINW*CM;
  int c0 = 2*t;
  float acc[8][2];
  #pragma unroll
  for (int r=0;r<8;r++){acc[r][0]=0.f;acc[r][1]=0.f;}
  for (int d=0; d<256; d+=4){
    float4 hv[8];
    #pragma unroll
    for (int r=0;r<8;r++) hv[r] = *(const float4*)&lh[r][d];
    #pragma unroll
    for (int dd=0;dd<4;dd++){
      float2 w = *(const float2*)(wm + (size_t)(d+dd)*CM + c0);
      #pragma unroll
      for (int r=0;r<8;r++){
        float hvv = ((const float*)&hv[r])[dd];
        acc[r][0] += hvv*w.x; acc[r][1] += hvv*w.y;
      }
    }
  }
  float* mst = ws + OFF_MST + ((size_t)e*NN + i0)*CM;
  #pragma unroll
  for (int r=0;r<8;r++) *(float2*)(mst + (size_t)r*CM + c0) = make_float2(acc[r][0],acc[r][1]);
  // continue over dynamic cols 256..298 -> M3 = mst + hs@wd
  const float* wd = wm + (size_t)256*CM;
  for (int d=0; d<SECW; d++){
    float2 w = *(const float2*)(wd + (size_t)d*CM + c0);
    #pragma unroll
    for (int r=0;r<8;r++){
      float hvv = lh2[r][d];
      acc[r][0] += hvv*w.x; acc[r][1] += hvv*w.y;
    }
  }
  float* m3 = ws + OFF_M3 + ((size_t)e*NN + i0)*CM;
  #pragma unroll
  for (int r=0;r<8;r++) *(float2*)(m3 + (size_t)r*CM + c0) = make_float2(acc[r][0],acc[r][1]);
  if (t<8){
    const float* wx = ws + OFF_WA3X + (size_t)e*FINW;
    float a=0.f;
    for (int d=0; d<256; d++) a += lh[t][d]*wx[d];
    ws[OFF_MSTX + (size_t)e*NN + i0 + t] = a;
    for (int d=0; d<SECW; d++) a += lh2[t][d]*wx[256+d];
    ws[OFF_M3X + (size_t)e*NN + i0 + t] = a;
  }
}

// ---------------- M3 recompute (g>=1) ----------------
__global__ void k_m3dyn(float* ws){
  int e=blockIdx.y, i0=blockIdx.x*8, t=threadIdx.x;
  __shared__ float lhs[8][44];
  const float* h = ws + OFF_H;
  for (int x=t; x<8*43; x+=64){ int r=x/43, d=x-r*43; lhs[r][d]=h[(size_t)(i0+r)*HSTR+256+d]; }
  __syncthreads();
  const float* wd  = ws + OFF_WA3 + ((size_t)e*FINW+256)*CM;
  const float* mst = ws + OFF_MST + ((size_t)e*NN+i0)*CM;
  int c0=2*t;
  float acc[8][2];
  #pragma unroll
  for (int r=0;r<8;r++){ float2 m=*(const float2*)(mst+(size_t)r*CM+c0); acc[r][0]=m.x; acc[r][1]=m.y; }
  for (int d=0; d<43; d++){
    float2 w=*(const float2*)(wd + (size_t)d*CM + c0);
    #pragma unroll
    for (int r=0;r<8;r++){ float hv=lhs[r][d]; acc[r][0]+=hv*w.x; acc[r][1]+=hv*w.y; }
  }
  float* m3 = ws + OFF_M3 + ((size_t)e*NN+i0)*CM;
  #pragma unroll
  for (int r=0;r<8;r++) *(float2*)(m3+(size_t)r*CM+c0)=make_float2(acc[r][0],acc[r][1]);
  if (t<8){
    float a = ws[OFF_MSTX + (size_t)e*NN+i0+t];
    const float* wx = ws + OFF_WA3X + (size_t)e*FINW + 256;
    for (int d=0;d<43;d++) a += lhs[t][d]*wx[d];
    ws[OFF_M3X + (size_t)e*NN+i0+t]=a;
  }
}

// gather (LDS-staged adjacency + 8 independent accumulators) + GRU update
__global__ void k_agg_gru(float* ws, const float* uz, const float* ur, const float* uh){
  int j=blockIdx.x, t=threadIdx.x;   // 128 threads
  __shared__ float lpre[C3];
  __shared__ float lhs[SECW];
  __shared__ float lrh[SECW];
  __shared__ int   ladj[DEG_CAP];
  float* h = ws + OFF_H;
  const int* cur =(const int*)(ws+OFF_CUR);
  const int* adjr=(const int*)(ws+OFF_ADJR) + (size_t)j*DEG_CAP;
  int cnt = cur[j]; if (cnt>DEG_CAP) cnt=DEG_CAP;
  for (int k=t;k<cnt;k+=128) ladj[k]=adjr[k];
  if (t<SECW) lhs[t] = h[(size_t)j*HSTR + 256 + t];
  __syncthreads();
  const float* M3=ws+OFF_M3; const float* M3X=ws+OFF_M3X;
  float a0 = ws[OFF_B3 + t];
  float ax = (t==0)? ws[OFF_B3+128] : 0.f;
  float p1=0.f,p2=0.f,p3=0.f,p4=0.f,p5=0.f,p6=0.f,p7=0.f;
  int k=0;
  for (; k+8<=cnt; k+=8){
    int r0=ladj[k],r1=ladj[k+1],r2=ladj[k+2],r3=ladj[k+3];
    int r4=ladj[k+4],r5=ladj[k+5],r6=ladj[k+6],r7=ladj[k+7];
    a0 += M3[(size_t)r0*CM+t];
    p1 += M3[(size_t)r1*CM+t];
    p2 += M3[(size_t)r2*CM+t];
    p3 += M3[(size_t)r3*CM+t];
    p4 += M3[(size_t)r4*CM+t];
    p5 += M3[(size_t)r5*CM+t];
    p6 += M3[(size_t)r6*CM+t];
    p7 += M3[(size_t)r7*CM+t];
    if (t==0) ax += ((M3X[r0]+M3X[r1])+(M3X[r2]+M3X[r3]))
                  + ((M3X[r4]+M3X[r5])+(M3X[r6]+M3X[r7]));
  }
  for (; k<cnt; k++){ int r=ladj[k]; a0+=M3[(size_t)r*CM+t]; if(t==0) ax+=M3X[r]; }
  a0 += ((p1+p2)+(p3+p4)) + ((p5+p6)+p7);
  lpre[t]=a0; if (t==0) lpre[128]=ax;
  __syncthreads();
  float z=0.f;
  if (t<SECW){
    float az=lpre[t], ar=lpre[43+t];
    for (int d=0;d<SECW;d++){ float hv=lhs[d]; az+=hv*uz[d*43+t]; ar+=hv*ur[d*43+t]; }
    z=sigm(az);
    float r=sigm(ar);
    lrh[t]=r*lhs[t];
  }
  __syncthreads();
  if (t<SECW){
    float ah=lpre[86+t];
    for (int d=0;d<SECW;d++) ah += lrh[d]*uh[d*43+t];
    float cand=tanh_(ah);
    h[(size_t)j*HSTR+256+t] = (1.f-z)*lhs[t] + z*cand;
  }
}

// ---------------- beat attention + layer-0 LSTM input projection (fused) ----------------
__global__ void k_attn_xw(float* ws, const float* mw, const float* mb, const float* mc,
                          const float* bw, const float* bb, const float* bc,
                          const float* res,
                          const float* w0f, const float* bia0f,
                          const float* w0b, const float* bia0b, float* xw){
  int b=blockIdx.x, t=threadIdx.x;  // 128 threads
  float* h=ws+OFF_H;
  __shared__ float sm[8][8];
  __shared__ float wgt[8][8];
  __shared__ float sb[8];
  __shared__ float wb_[8];
  __shared__ float lb[52];
  int n=t>>3, hh=t&7;
  if (t<64){
    const float* mrow = h + (size_t)(b*8+n)*HSTR + 267;
    float sim=0.f;
    for (int d=0;d<4;d++){
      int c=hh*4+d;
      float acc=mb[c];
      for (int k=0;k<32;k++) acc += mrow[k]*mw[k*32+c];
      sim += tanh_(acc)*mc[c];
    }
    sm[n][hh]=sim;
  }
  if (t<8){
    const float* irow = h + (size_t)(b*8+t)*HSTR + 256;
    float sim=0.f;
    for (int d=0;d<11;d++){
      float acc=bb[d];
      for (int k=0;k<11;k++) acc += irow[k]*bw[k*11+d];
      sim += tanh_(acc)*bc[d];
    }
    sb[t]=sim;
  }
  __syncthreads();
  if (t<64){
    float m=-1e30f;
    for (int q=0;q<8;q++) m=fmaxf(m, sm[q][hh]);
    float Z=0.f;
    for (int q=0;q<8;q++) Z+=__expf(sm[q][hh]-m);
    wgt[n][hh]=__expf(sm[n][hh]-m)/Z;
  }
  if (t<8){
    float m=-1e30f;
    for (int q=0;q<8;q++) m=fmaxf(m, sb[q]);
    float Z=0.f;
    for (int q=0;q<8;q++) Z+=__expf(sb[q]-m);
    wb_[t]=__expf(sb[t]-m)/Z;
  }
  __syncthreads();
  if (t<32){
    int hh2=t>>2;
    float acc=0.f;
    for (int q=0;q<8;q++) acc += wgt[q][hh2]* h[(size_t)(b*8+q)*HSTR + 267 + t];
    lb[11+t]=acc;
  }
  if (t<11){
    float acc=0.f;
    for (int q=0;q<8;q++) acc += wb_[q]* h[(size_t)(b*8+q)*HSTR + 256 + t];
    lb[t]=acc;
  }
  if (t<8) lb[43+t]=res[b*8+t];
  __syncthreads();
  float acc0=bia0f[t], acc1=bia0b[t];
  for (int k=0;k<51;k++){
    float v=lb[k];
    acc0 += v*w0f[t*51+k];
    acc1 += v*w0b[t*51+k];
  }
  xw[((size_t)0*NBEAT + b)*128 + t]=acc0;
  xw[((size_t)1*NBEAT + b)*128 + t]=acc1;
}

// ---------------- LSTM layer-1 input projection ----------------
__global__ void k_xw(const float* inp, int din, const float* wf, const float* bf_,
                     const float* wb, const float* bb_, float* xw){
  int bid=blockIdx.x; int tt=bid>>1, dir=bid&1;
  const float* w = dir? wb:wf; const float* bia = dir? bb_:bf_;
  __shared__ float rowl[64];
  int t=threadIdx.x;   // 128 threads
  if (t<din) rowl[t]=inp[(size_t)tt*din+t];
  __syncthreads();
  float acc=bia[t];
  for (int k=0;k<din;k++) acc += rowl[k]*w[t*din+k];
  xw[((size_t)dir*NBEAT + tt)*128 + t]=acc;
}

// R5/R10 scan verbatim (PASSED @87us): one wave per direction; lane l<32: i_l,g_l; l>=32: f,o;
// c in high lanes. h via LDS (no inner wave_barriers!); x staged in 8-step LDS chunks.
#define CH 8
__global__ __launch_bounds__(64,1) void k_scan(const float* xw, const float* whh_f,
                                               const float* whh_b, float* out){
  int dir = blockIdx.x;
  int l = threadIdx.x;
  const float* whh = dir ? whh_b : whh_f;
  float4 rA[8], rB[8];
  #pragma unroll
  for (int q=0;q<8;q++){
    rA[q] = *(const float4*)&whh[l*32 + q*4];
    rB[q] = *(const float4*)&whh[(l+64)*32 + q*4];
  }
  __shared__ __align__(16) float xb[2][CH*128];
  __shared__ __align__(16) float lds_h[32];
  if (l<32) lds_h[l]=0.f;
  const float* x = xw + (size_t)dir*NBEAT*128;
  int half = l>>5, q4 = l&31;
  int stp = dir ? -1 : 1;
  float4 st[4];
  #pragma unroll
  for (int r=0;r<4;r++){
    int s = 2*r + half;
    int ti = dir ? (NBEAT-1-s) : s;
    st[r] = ((const float4*)&x[ti*128])[q4];
  }
  #pragma unroll
  for (int r=0;r<4;r++){ int u=2*r+half; ((float4*)&xb[0][u*128])[q4]=st[r]; }
  __builtin_amdgcn_wave_barrier();
  float creg = 0.f;
  int tt = dir ? NBEAT-1 : 0;
  for (int c=0;c<NBEAT/CH;c++){
    int buf = c&1;
    if (c+1 < NBEAT/CH){       // issue next chunk's global loads now (consumed at chunk end)
      #pragma unroll
      for (int r=0;r<4;r++){
        int s = (c+1)*CH + 2*r + half;
        int ti = dir ? (NBEAT-1-s) : s;
        st[r] = ((const float4*)&x[ti*128])[q4];
      }
    }
    #pragma unroll
    for (int u=0;u<CH;u++){
      float cxA = xb[buf][u*128 + l];
      float cxB = xb[buf][u*128 + 64 + l];
      float4 hv[8];
      #pragma unroll
      for (int q=0;q<8;q++) hv[q] = *(const float4*)&lds_h[q*4];   // broadcast reads
      float a[8], bq[8];
      #pragma unroll
      for (int q=0;q<8;q++){
        float4 h4=hv[q], wa=rA[q], wb=rB[q];
        a[q]  = h4.x*wa.x + h4.y*wa.y + h4.z*wa.z + h4.w*wa.w;
        bq[q] = h4.x*wb.x + h4.y*wb.y + h4.z*wb.z + h4.w*wb.w;
      }
      float accA = cxA + ((a[0]+a[1])+(a[2]+a[3])) + ((a[4]+a[5])+(a[6]+a[7]));
      float accB = cxB + ((bq[0]+bq[1])+(bq[2]+bq[3])) + ((bq[4]+bq[5])+(bq[6]+bq[7]));
      float pA  = sigm(accA);      // sigm(i) low lanes, sigm(f) high lanes
      float pBt = tanh_(accB);     // tanh(g) low lanes
      float pBs = sigm(accB);      // sigm(o) high lanes
      float prod = pA * pBt;
      float prodIn = __shfl(prod, l & 31, 64);
      creg = pA*creg + prodIn;     // c update (high lanes valid)
      float hnew = pBs * tanh_(creg);
      if (l>=32){
        lds_h[l&31] = hnew;        // program order + LDS aliasing keep write->read ordered in-wave
        out[(size_t)tt*64 + dir*32 + (l&31)] = hnew;
      }
      tt += stp;
    }
    if (c+1 < NBEAT/CH){
      #pragma unroll
      for (int r=0;r<4;r++){ int u=2*r+half; ((float4*)&xb[1-buf][u*128])[q4]=st[r]; }
      __builtin_amdgcn_wave_barrier();
    }
  }
}

// ---------------- fc head + final_out + h update (tempo fused) ----------------
__global__ void k_fc(float* ws, const int* bn, const float* w1, const float* b1,
                     const float* w2, const float* b2,
                     const float* wt, const float* bt, float* dout, int it){
  int i=blockIdx.x, t=threadIdx.x;   // 64 threads
  __shared__ float row[FINW];
  __shared__ float hid[32];
  __shared__ float fo[11];
  float* h=ws+OFF_H;
  int b = bn[i];
  const float* rnn = ws+OFF_RNN1;
  for (int c=t;c<FINW;c+=64){
    float v;
    if (c>=192 && c<256){ v=rnn[(size_t)b*64 + c-192]; h[(size_t)i*HSTR+c]=v; }
    else v=h[(size_t)i*HSTR+c];
    row[c]=v;
  }
  float tv = rnn[(size_t)b*64 + t]*wt[t];
  #pragma unroll
  for (int off=32; off; off>>=1) tv += __shfl_xor(tv, off, 64);
  __syncthreads();
  if (t<32){
    float acc=b1[t];
    for (int k=0;k<FINW;k++) acc += row[k]*w1[k*32+t];
    hid[t]=fmaxf(acc,0.f);
  }
  __syncthreads();
  if (t<10){
    float acc=b2[t];
    for (int m=0;m<32;m++) acc += hid[m]*w2[m*10+t];
    fo[1+t]=acc;
  }
  if (t==0) fo[0]=tv + bt[0];
  __syncthreads();
  if (t<11){
    float v=fo[t];
    h[(size_t)i*HSTR+256+t]=v;
    dout[(size_t)(2+it)*17600 + i*11 + t]=v;
    if (it==1) dout[i*11+t]=v;
  }
}

// ---------------- launcher ----------------
extern "C" void kernel_launch(void* const* d_in, const int* in_sizes, int n_in,
                              void* d_out, int out_size, void* d_ws, size_t ws_size,
                              hipStream_t stream){
  (void)in_sizes; (void)n_in; (void)out_size; (void)ws_size;
  float* ws=(float*)d_ws;
  const float* note    =(const float*)d_in[0];
  const float* pv      =(const float*)d_in[1];
  const float* res     =(const float*)d_in[2];
  const float* edges   =(const float*)d_in[3];
  const int*   bn      =(const int*)d_in[4];
  const float* w_style =(const float*)d_in[5];
  const float* b_style =(const float*)d_in[6];
  const float* w_init1 =(const float*)d_in[7];
  const float* b_init1 =(const float*)d_in[8];
  const float* w_init2 =(const float*)d_in[9];
  const float* b_init2 =(const float*)d_in[10];
  const float* gg_wa   =(const float*)d_in[11];
  const float* gg_ba   =(const float*)d_in[12];
  const float* gg_wz   =(const float*)d_in[13];
  const float* gg_wr   =(const float*)d_in[14];
  const float* gg_wh   =(const float*)d_in[15];
  const float* gg_uz   =(const float*)d_in[16];
  const float* gg_ur   =(const float*)d_in[17];
  const float* gg_uh   =(const float*)d_in[18];
  const float* abw     =(const float*)d_in[19];
  const float* abb     =(const float*)d_in[20];
  const float* abc     =(const float*)d_in[21];
  const float* amw     =(const float*)d_in[22];
  const float* amb     =(const float*)d_in[23];
  const float* amc     =(const float*)d_in[24];
  const float* wih0f   =(const float*)d_in[25];
  const float* whh0f   =(const float*)d_in[26];
  const float* b0f     =(const float*)d_in[27];
  const float* wih0b   =(const float*)d_in[28];
  const float* whh0b   =(const float*)d_in[29];
  const float* b0b     =(const float*)d_in[30];
  const float* wih1f   =(const float*)d_in[31];
  const float* whh1f   =(const float*)d_in[32];
  const float* b1f     =(const float*)d_in[33];
  const float* wih1b   =(const float*)d_in[34];
  const float* whh1b   =(const float*)d_in[35];
  const float* b1b     =(const float*)d_in[36];
  const float* w_tempo =(const float*)d_in[37];
  const float* b_tempo =(const float*)d_in[38];
  const float* w_fc1   =(const float*)d_in[39];
  const float* b_fc1   =(const float*)d_in[40];
  const float* w_fc2   =(const float*)d_in[41];
  const float* b_fc2   =(const float*)d_in[42];
  float* dout=(float*)d_out;

  hipMemsetAsync(ws+OFF_CUR, 0, NN*sizeof(int), stream);
  k_setup<<<NB_WA3+NB_INIT+NB_ADJ,128,0,stream>>>(
      gg_wa,gg_ba,gg_wz,gg_wr,gg_wh,
      note,pv,w_style,b_style,w_init1,b_init1,w_init2,b_init2,
      edges,ws,dout);

  for (int it=0; it<2; it++){
    k_mstat<<<dim3(200,12),64,0,stream>>>(ws);      // also emits M3(h0)
    k_agg_gru<<<NN,128,0,stream>>>(ws,gg_uz,gg_ur,gg_uh);          // g=0
    for (int g=1; g<3; g++){
      k_m3dyn<<<dim3(200,12),64,0,stream>>>(ws);
      k_agg_gru<<<NN,128,0,stream>>>(ws,gg_uz,gg_ur,gg_uh);
    }
    k_attn_xw<<<NBEAT,128,0,stream>>>(ws,amw,amb,amc,abw,abb,abc,res,
                                      wih0f,b0f,wih0b,b0b,ws+OFF_XW);
    k_scan<<<2,64,0,stream>>>(ws+OFF_XW,whh0f,whh0b,ws+OFF_RNN0);
    k_xw<<<2*NBEAT,128,0,stream>>>(ws+OFF_RNN0,64,wih1f,b1f,wih1b,b1b,ws+OFF_XW);
    k_scan<<<2,64,0,stream>>>(ws+OFF_XW,whh1f,whh1b,ws+OFF_RNN1);
    k_fc<<<NN,64,0,stream>>>(ws,bn,w_fc1,b_fc1,w_fc2,b_fc2,w_tempo,b_tempo,dout,it);
  }
}

// Round 15
// 919.629 us; speedup vs baseline: 3.3305x; 1.0097x over previous
//
#include <hip/hip_runtime.h>
#include <stdint.h>

// ---------------- problem constants ----------------
#define NN     1600
#define NBEAT  200
#define FINW   299
#define HSTR   300      // padded row stride for h
#define SECW   43
#define EDG    12
#define C3     129      // 3*43 projected width
#define CM     128      // main columns (129th handled separately)
#define DEG_CAP 256     // per-destination adjacency bucket (mean 77, max~112)

// fused-setup block ranges (all 128-thread blocks); adj FIRST so the memory-bound
// scan starts immediately and overlaps the compute-bound wa3/init blocks.
#define NB_ADJ  3840
#define NB_WA3  (EDG*FINW+1)          // 3589
#define NB_INIT NN                    // 1600

__device__ __forceinline__ float sigm(float x){ return 1.0f/(1.0f+__expf(-x)); }
__device__ __forceinline__ float tanh_(float x){ return 2.0f/(1.0f+__expf(-2.0f*x)) - 1.0f; }

// ---------------- workspace layout (4-byte words) ----------------
constexpr size_t OFF_H    = 0;                                   // 1600*300
constexpr size_t OFF_WA3  = OFF_H    + (size_t)NN*HSTR;          // 12*299*128
constexpr size_t OFF_WA3X = OFF_WA3  + (size_t)EDG*FINW*CM;      // 12*299
constexpr size_t OFF_B3   = OFF_WA3X + (size_t)EDG*FINW;         // 132
constexpr size_t OFF_MST  = OFF_B3   + 132;                      // 12*1600*128
constexpr size_t OFF_MSTX = OFF_MST  + (size_t)EDG*NN*CM;        // 12*1600
constexpr size_t OFF_M3   = OFF_MSTX + (size_t)EDG*NN;           // 12*1600*128
constexpr size_t OFF_M3X  = OFF_M3   + (size_t)EDG*NN*CM;        // 12*1600
constexpr size_t OFF_CUR  = OFF_M3X  + (size_t)EDG*NN;           // 1600 ints (degree counters)
constexpr size_t OFF_ADJR = OFF_CUR  + NN;                       // 1600*256 ints
constexpr size_t OFF_XW   = OFF_ADJR + (size_t)NN*DEG_CAP;       // 2*200*128
constexpr size_t OFF_RNN0 = OFF_XW   + (size_t)2*NBEAT*128;      // 200*64
constexpr size_t OFF_RNN1 = OFF_RNN0 + (size_t)NBEAT*64;         // 200*64

// ---------------- fused setup: adj | wa3 | init (independent work, one dispatch) ----------------
__global__ __launch_bounds__(128) void k_setup(
    const float* wa, const float* ba, const float* wz, const float* wr, const float* wh,
    const float* note, const float* pv, const float* w_style, const float* b_style,
    const float* w1, const float* b1, const float* w2, const float* b2,
    const float* edges, float* ws, float* dout){
  int blk = blockIdx.x;
  int t = threadIdx.x;
  if (blk < NB_ADJ){
    // ---- adj: sparse edge extraction into fixed-width buckets.
    // 4-deep load batching: 4 outstanding strided uint4 loads per thread per batch.
    int* cur  = (int*)(ws + OFF_CUR);
    int* adjr = (int*)(ws + OFF_ADJR);
    const uint4* p = (const uint4*)edges;
    const unsigned int nvec = 7680000u;   // 12*1600*1600/4
    const unsigned int stride = (unsigned int)NB_ADJ*128u;
    unsigned int v0 = (unsigned int)blk*128u + t;
    for (unsigned int b0 = v0; b0 < nvec; b0 += 4u*stride){
      unsigned int v1=b0+stride, v2=b0+2u*stride, v3=b0+3u*stride;
      bool g1=v1<nvec, g2=v2<nvec, g3=v3<nvec;
      uint4 w0 = p[b0];
      uint4 w1v = g1 ? p[v1] : make_uint4(0,0,0,0);
      uint4 w2v = g2 ? p[v2] : make_uint4(0,0,0,0);
      uint4 w3v = g3 ? p[v3] : make_uint4(0,0,0,0);
      uint4 wv[4] = {w0,w1v,w2v,w3v};
      unsigned int vv[4] = {b0,v1,v2,v3};
      #pragma unroll
      for (int u=0; u<4; u++){
        uint4 w = wv[u];
        if ((w.x|w.y|w.z|w.w)==0u) continue;
        unsigned int base = vv[u]*4u;
        unsigned int arr[4]={w.x,w.y,w.z,w.w};
        #pragma unroll
        for (int q=0;q<4;q++){
          if (arr[q]){
            unsigned int idx=base+q;
            unsigned int j=idx%1600u;
            int slot=atomicAdd(&cur[j],1);
            if (slot<DEG_CAP) adjr[j*DEG_CAP + slot]=(int)(idx/1600u);  // row = e*1600+i
          }
        }
      }
    }
  } else if (blk < NB_ADJ + NB_WA3){
    // ---- wa3: wa3[e][d][c] = sum_s wa[e][d][s]*Wcat[s][c]; last block does b3 ----
    int b = blk - NB_ADJ;
    bool isB = (b == EDG*FINW);
    int e = b/FINW, d = b - e*FINW;
    __shared__ float lrow[FINW];
    const float* row = isB ? ba : (wa + ((size_t)e*FINW + d)*FINW);
    for (int s=t; s<FINW; s+=128) lrow[s]=row[s];
    __syncthreads();
    for (int c=t; c<C3; c+=128){
      const float* Wp; int cc;
      if (c<43){Wp=wz; cc=c;} else if (c<86){Wp=wr; cc=c-43;} else {Wp=wh; cc=c-86;}
      float acc=0.f;
      for (int s=0;s<FINW;s++) acc += lrow[s]*Wp[s*43+cc];
      if (isB) ws[OFF_B3 + c] = acc;
      else if (c<CM) ws[OFF_WA3 + ((size_t)e*FINW+d)*CM + c] = acc;
      else           ws[OFF_WA3X + (size_t)e*FINW + d]       = acc;
    }
  } else {
    // ---- init: perf_z + init_out + assemble h row; writes total[0] ----
    int i = blk - NB_ADJ - NB_WA3;
    __shared__ float lnote[128];
    __shared__ float lh1[64];
    __shared__ float lo[11];
    __shared__ float lperf[64];
    lnote[t]=note[i*128+t];
    if (t>=64){
      int u=t-64;
      float acc=b_style[u];
      for (int k=0;k<16;k++) acc += pv[k]*w_style[k*64+u];
      lperf[u]=fmaxf(acc,0.f);
    }
    __syncthreads();
    if (t<64){
      float acc=b1[t];
      for (int k=0;k<128;k++) acc += lnote[k]*w1[k*64+t];
      lh1[t]=fmaxf(acc,0.f);
    }
    __syncthreads();
    if (t<11){
      float acc=b2[t];
      for (int s=0;s<64;s++) acc += lh1[s]*w2[s*11+t];
      lo[t]=acc;
      dout[17600 + i*11 + t] = acc;
    }
    __syncthreads();
    for (int c=t;c<FINW;c+=128){
      float v;
      if (c<128)      v=lnote[c];
      else if (c<192) v=lperf[c-128];
      else if (c<256) v=0.f;
      else if (c<267) v=lo[c-256];
      else            v=0.f;
      ws[OFF_H + (size_t)i*HSTR + c]=v;
    }
  }
}

// ---------------- static message part + M3(h0) (once per seq-iter) ----------------
__global__ void k_mstat(float* ws){
  int e = blockIdx.y; int i0 = blockIdx.x*8;
  int t = threadIdx.x;
  __shared__ float lh[8][256];
  __shared__ float lh2[8][44];
  const float* h = ws + OFF_H;
  for (int x=t; x<512; x+=64){
    int r = x>>6, dq = x&63;
    ((float4*)&lh[r][0])[dq] = ((const float4*)(h + (size_t)(i0+r)*HSTR))[dq];
  }
  for (int x=t; x<88; x+=64){
    int r = x/11, dq = x-r*11;
    ((float4*)&lh2[r][0])[dq] = ((const float4*)(h + (size_t)(i0+r)*HSTR + 256))[dq];
  }
  __syncthreads();
  const float* wm = ws + OFF_WA3 + (size_t)e*FINW*CM;
  int c0 = 2*t;
  float acc[8][2];
  #pragma unroll
  for (int r=0;r<8;r++){acc[r][0]=0.f;acc[r][1]=0.f;}
  for (int d=0; d<256; d+=4){
    float4 hv[8];
    #pragma unroll
    for (int r=0;r<8;r++) hv[r] = *(const float4*)&lh[r][d];
    #pragma unroll
    for (int dd=0;dd<4;dd++){
      float2 w = *(const float2*)(wm + (size_t)(d+dd)*CM + c0);
      #pragma unroll
      for (int r=0;r<8;r++){
        float hvv = ((const float*)&hv[r])[dd];
        acc[r][0] += hvv*w.x; acc[r][1] += hvv*w.y;
      }
    }
  }
  float* mst = ws + OFF_MST + ((size_t)e*NN + i0)*CM;
  #pragma unroll
  for (int r=0;r<8;r++) *(float2*)(mst + (size_t)r*CM + c0) = make_float2(acc[r][0],acc[r][1]);
  // continue over dynamic cols 256..298 -> M3 = mst + hs@wd
  const float* wd = wm + (size_t)256*CM;
  for (int d=0; d<SECW; d++){
    float2 w = *(const float2*)(wd + (size_t)d*CM + c0);
    #pragma unroll
    for (int r=0;r<8;r++){
      float hvv = lh2[r][d];
      acc[r][0] += hvv*w.x; acc[r][1] += hvv*w.y;
    }
  }
  float* m3 = ws + OFF_M3 + ((size_t)e*NN + i0)*CM;
  #pragma unroll
  for (int r=0;r<8;r++) *(float2*)(m3 + (size_t)r*CM + c0) = make_float2(acc[r][0],acc[r][1]);
  if (t<8){
    const float* wx = ws + OFF_WA3X + (size_t)e*FINW;
    float a=0.f;
    for (int d=0; d<256; d++) a += lh[t][d]*wx[d];
    ws[OFF_MSTX + (size_t)e*NN + i0 + t] = a;
    for (int d=0; d<SECW; d++) a += lh2[t][d]*wx[256+d];
    ws[OFF_M3X + (size_t)e*NN + i0 + t] = a;
  }
}

// ---------------- M3 recompute (g>=1) ----------------
__global__ void k_m3dyn(float* ws){
  int e=blockIdx.y, i0=blockIdx.x*8, t=threadIdx.x;
  __shared__ float lhs[8][44];
  const float* h = ws + OFF_H;
  for (int x=t; x<8*43; x+=64){ int r=x/43, d=x-r*43; lhs[r][d]=h[(size_t)(i0+r)*HSTR+256+d]; }
  __syncthreads();
  const float* wd  = ws + OFF_WA3 + ((size_t)e*FINW+256)*CM;
  const float* mst = ws + OFF_MST + ((size_t)e*NN+i0)*CM;
  int c0=2*t;
  float acc[8][2];
  #pragma unroll
  for (int r=0;r<8;r++){ float2 m=*(const float2*)(mst+(size_t)r*CM+c0); acc[r][0]=m.x; acc[r][1]=m.y; }
  for (int d=0; d<43; d++){
    float2 w=*(const float2*)(wd + (size_t)d*CM + c0);
    #pragma unroll
    for (int r=0;r<8;r++){ float hv=lhs[r][d]; acc[r][0]+=hv*w.x; acc[r][1]+=hv*w.y; }
  }
  float* m3 = ws + OFF_M3 + ((size_t)e*NN+i0)*CM;
  #pragma unroll
  for (int r=0;r<8;r++) *(float2*)(m3+(size_t)r*CM+c0)=make_float2(acc[r][0],acc[r][1]);
  if (t<8){
    float a = ws[OFF_MSTX + (size_t)e*NN+i0+t];
    const float* wx = ws + OFF_WA3X + (size_t)e*FINW + 256;
    for (int d=0;d<43;d++) a += lhs[t][d]*wx[d];
    ws[OFF_M3X + (size_t)e*NN+i0+t]=a;
  }
}

// gather (LDS-staged adjacency + 8 independent accumulators) + GRU update
__global__ void k_agg_gru(float* ws, const float* uz, const float* ur, const float* uh){
  int j=blockIdx.x, t=threadIdx.x;   // 128 threads
  __shared__ float lpre[C3];
  __shared__ float lhs[SECW];
  __shared__ float lrh[SECW];
  __shared__ int   ladj[DEG_CAP];
  float* h = ws + OFF_H;
  const int* cur =(const int*)(ws+OFF_CUR);
  const int* adjr=(const int*)(ws+OFF_ADJR) + (size_t)j*DEG_CAP;
  int cnt = cur[j]; if (cnt>DEG_CAP) cnt=DEG_CAP;
  for (int k=t;k<cnt;k+=128) ladj[k]=adjr[k];
  if (t<SECW) lhs[t] = h[(size_t)j*HSTR + 256 + t];
  __syncthreads();
  const float* M3=ws+OFF_M3; const float* M3X=ws+OFF_M3X;
  float a0 = ws[OFF_B3 + t];
  float ax = (t==0)? ws[OFF_B3+128] : 0.f;
  float p1=0.f,p2=0.f,p3=0.f,p4=0.f,p5=0.f,p6=0.f,p7=0.f;
  int k=0;
  for (; k+8<=cnt; k+=8){
    int r0=ladj[k],r1=ladj[k+1],r2=ladj[k+2],r3=ladj[k+3];
    int r4=ladj[k+4],r5=ladj[k+5],r6=ladj[k+6],r7=ladj[k+7];
    a0 += M3[(size_t)r0*CM+t];
    p1 += M3[(size_t)r1*CM+t];
    p2 += M3[(size_t)r2*CM+t];
    p3 += M3[(size_t)r3*CM+t];
    p4 += M3[(size_t)r4*CM+t];
    p5 += M3[(size_t)r5*CM+t];
    p6 += M3[(size_t)r6*CM+t];
    p7 += M3[(size_t)r7*CM+t];
    if (t==0) ax += ((M3X[r0]+M3X[r1])+(M3X[r2]+M3X[r3]))
                  + ((M3X[r4]+M3X[r5])+(M3X[r6]+M3X[r7]));
  }
  for (; k<cnt; k++){ int r=ladj[k]; a0+=M3[(size_t)r*CM+t]; if(t==0) ax+=M3X[r]; }
  a0 += ((p1+p2)+(p3+p4)) + ((p5+p6)+p7);
  lpre[t]=a0; if (t==0) lpre[128]=ax;
  __syncthreads();
  float z=0.f;
  if (t<SECW){
    float az=lpre[t], ar=lpre[43+t];
    for (int d=0;d<SECW;d++){ float hv=lhs[d]; az+=hv*uz[d*43+t]; ar+=hv*ur[d*43+t]; }
    z=sigm(az);
    float r=sigm(ar);
    lrh[t]=r*lhs[t];
  }
  __syncthreads();
  if (t<SECW){
    float ah=lpre[86+t];
    for (int d=0;d<SECW;d++) ah += lrh[d]*uh[d*43+t];
    float cand=tanh_(ah);
    h[(size_t)j*HSTR+256+t] = (1.f-z)*lhs[t] + z*cand;
  }
}

// ---------------- beat attention + layer-0 LSTM input projection (fused) ----------------
__global__ void k_attn_xw(float* ws, const float* mw, const float* mb, const float* mc,
                          const float* bw, const float* bb, const float* bc,
                          const float* res,
                          const float* w0f, const float* bia0f,
                          const float* w0b, const float* bia0b, float* xw){
  int b=blockIdx.x, t=threadIdx.x;  // 128 threads
  float* h=ws+OFF_H;
  __shared__ float sm[8][8];
  __shared__ float wgt[8][8];
  __shared__ float sb[8];
  __shared__ float wb_[8];
  __shared__ float lb[52];
  int n=t>>3, hh=t&7;
  if (t<64){
    const float* mrow = h + (size_t)(b*8+n)*HSTR + 267;
    float sim=0.f;
    for (int d=0;d<4;d++){
      int c=hh*4+d;
      float acc=mb[c];
      for (int k=0;k<32;k++) acc += mrow[k]*mw[k*32+c];
      sim += tanh_(acc)*mc[c];
    }
    sm[n][hh]=sim;
  }
  if (t<8){
    const float* irow = h + (size_t)(b*8+t)*HSTR + 256;
    float sim=0.f;
    for (int d=0;d<11;d++){
      float acc=bb[d];
      for (int k=0;k<11;k++) acc += irow[k]*bw[k*11+d];
      sim += tanh_(acc)*bc[d];
    }
    sb[t]=sim;
  }
  __syncthreads();
  if (t<64){
    float m=-1e30f;
    for (int q=0;q<8;q++) m=fmaxf(m, sm[q][hh]);
    float Z=0.f;
    for (int q=0;q<8;q++) Z+=__expf(sm[q][hh]-m);
    wgt[n][hh]=__expf(sm[n][hh]-m)/Z;
  }
  if (t<8){
    float m=-1e30f;
    for (int q=0;q<8;q++) m=fmaxf(m, sb[q]);
    float Z=0.f;
    for (int q=0;q<8;q++) Z+=__expf(sb[q]-m);
    wb_[t]=__expf(sb[t]-m)/Z;
  }
  __syncthreads();
  if (t<32){
    int hh2=t>>2;
    float acc=0.f;
    for (int q=0;q<8;q++) acc += wgt[q][hh2]* h[(size_t)(b*8+q)*HSTR + 267 + t];
    lb[11+t]=acc;
  }
  if (t<11){
    float acc=0.f;
    for (int q=0;q<8;q++) acc += wb_[q]* h[(size_t)(b*8+q)*HSTR + 256 + t];
    lb[t]=acc;
  }
  if (t<8) lb[43+t]=res[b*8+t];
  __syncthreads();
  float acc0=bia0f[t], acc1=bia0b[t];
  for (int k=0;k<51;k++){
    float v=lb[k];
    acc0 += v*w0f[t*51+k];
    acc1 += v*w0b[t*51+k];
  }
  xw[((size_t)0*NBEAT + b)*128 + t]=acc0;
  xw[((size_t)1*NBEAT + b)*128 + t]=acc1;
}

// ---------------- LSTM layer-1 input projection ----------------
__global__ void k_xw(const float* inp, int din, const float* wf, const float* bf_,
                     const float* wb, const float* bb_, float* xw){
  int bid=blockIdx.x; int tt=bid>>1, dir=bid&1;
  const float* w = dir? wb:wf; const float* bia = dir? bb_:bf_;
  __shared__ float rowl[64];
  int t=threadIdx.x;   // 128 threads
  if (t<din) rowl[t]=inp[(size_t)tt*din+t];
  __syncthreads();
  float acc=bia[t];
  for (int k=0;k<din;k++) acc += rowl[k]*w[t*din+k];
  xw[((size_t)dir*NBEAT + tt)*128 + t]=acc;
}

// R5/R10 scan verbatim (PASSED @87us): one wave per direction; lane l<32: i_l,g_l; l>=32: f,o;
// c in high lanes. h via LDS (no inner wave_barriers!); x staged in 8-step LDS chunks.
#define CH 8
__global__ __launch_bounds__(64,1) void k_scan(const float* xw, const float* whh_f,
                                               const float* whh_b, float* out){
  int dir = blockIdx.x;
  int l = threadIdx.x;
  const float* whh = dir ? whh_b : whh_f;
  float4 rA[8], rB[8];
  #pragma unroll
  for (int q=0;q<8;q++){
    rA[q] = *(const float4*)&whh[l*32 + q*4];
    rB[q] = *(const float4*)&whh[(l+64)*32 + q*4];
  }
  __shared__ __align__(16) float xb[2][CH*128];
  __shared__ __align__(16) float lds_h[32];
  if (l<32) lds_h[l]=0.f;
  const float* x = xw + (size_t)dir*NBEAT*128;
  int half = l>>5, q4 = l&31;
  int stp = dir ? -1 : 1;
  float4 st[4];
  #pragma unroll
  for (int r=0;r<4;r++){
    int s = 2*r + half;
    int ti = dir ? (NBEAT-1-s) : s;
    st[r] = ((const float4*)&x[ti*128])[q4];
  }
  #pragma unroll
  for (int r=0;r<4;r++){ int u=2*r+half; ((float4*)&xb[0][u*128])[q4]=st[r]; }
  __builtin_amdgcn_wave_barrier();
  float creg = 0.f;
  int tt = dir ? NBEAT-1 : 0;
  for (int c=0;c<NBEAT/CH;c++){
    int buf = c&1;
    if (c+1 < NBEAT/CH){       // issue next chunk's global loads now (consumed at chunk end)
      #pragma unroll
      for (int r=0;r<4;r++){
        int s = (c+1)*CH + 2*r + half;
        int ti = dir ? (NBEAT-1-s) : s;
        st[r] = ((const float4*)&x[ti*128])[q4];
      }
    }
    #pragma unroll
    for (int u=0;u<CH;u++){
      float cxA = xb[buf][u*128 + l];
      float cxB = xb[buf][u*128 + 64 + l];
      float4 hv[8];
      #pragma unroll
      for (int q=0;q<8;q++) hv[q] = *(const float4*)&lds_h[q*4];   // broadcast reads
      float a[8], bq[8];
      #pragma unroll
      for (int q=0;q<8;q++){
        float4 h4=hv[q], wa=rA[q], wb=rB[q];
        a[q]  = h4.x*wa.x + h4.y*wa.y + h4.z*wa.z + h4.w*wa.w;
        bq[q] = h4.x*wb.x + h4.y*wb.y + h4.z*wb.z + h4.w*wb.w;
      }
      float accA = cxA + ((a[0]+a[1])+(a[2]+a[3])) + ((a[4]+a[5])+(a[6]+a[7]));
      float accB = cxB + ((bq[0]+bq[1])+(bq[2]+bq[3])) + ((bq[4]+bq[5])+(bq[6]+bq[7]));
      float pA  = sigm(accA);      // sigm(i) low lanes, sigm(f) high lanes
      float pBt = tanh_(accB);     // tanh(g) low lanes
      float pBs = sigm(accB);      // sigm(o) high lanes
      float prod = pA * pBt;
      float prodIn = __shfl(prod, l & 31, 64);
      creg = pA*creg + prodIn;     // c update (high lanes valid)
      float hnew = pBs * tanh_(creg);
      if (l>=32){
        lds_h[l&31] = hnew;        // program order + LDS aliasing keep write->read ordered in-wave
        out[(size_t)tt*64 + dir*32 + (l&31)] = hnew;
      }
      tt += stp;
    }
    if (c+1 < NBEAT/CH){
      #pragma unroll
      for (int r=0;r<4;r++){ int u=2*r+half; ((float4*)&xb[1-buf][u*128])[q4]=st[r]; }
      __builtin_amdgcn_wave_barrier();
    }
  }
}

// ---------------- fc head + final_out + h update (tempo fused) ----------------
__global__ void k_fc(float* ws, const int* bn, const float* w1, const float* b1,
                     const float* w2, const float* b2,
                     const float* wt, const float* bt, float* dout, int it){
  int i=blockIdx.x, t=threadIdx.x;   // 64 threads
  __shared__ float row[FINW];
  __shared__ float hid[32];
  __shared__ float fo[11];
  float* h=ws+OFF_H;
  int b = bn[i];
  const float* rnn = ws+OFF_RNN1;
  for (int c=t;c<FINW;c+=64){
    float v;
    if (c>=192 && c<256){ v=rnn[(size_t)b*64 + c-192]; h[(size_t)i*HSTR+c]=v; }
    else v=h[(size_t)i*HSTR+c];
    row[c]=v;
  }
  float tv = rnn[(size_t)b*64 + t]*wt[t];
  #pragma unroll
  for (int off=32; off; off>>=1) tv += __shfl_xor(tv, off, 64);
  __syncthreads();
  if (t<32){
    float acc=b1[t];
    for (int k=0;k<FINW;k++) acc += row[k]*w1[k*32+t];
    hid[t]=fmaxf(acc,0.f);
  }
  __syncthreads();
  if (t<10){
    float acc=b2[t];
    for (int m=0;m<32;m++) acc += hid[m]*w2[m*10+t];
    fo[1+t]=acc;
  }
  if (t==0) fo[0]=tv + bt[0];
  __syncthreads();
  if (t<11){
    float v=fo[t];
    h[(size_t)i*HSTR+256+t]=v;
    dout[(size_t)(2+it)*17600 + i*11 + t]=v;
    if (it==1) dout[i*11+t]=v;
  }
}

// ---------------- launcher ----------------
extern "C" void kernel_launch(void* const* d_in, const int* in_sizes, int n_in,
                              void* d_out, int out_size, void* d_ws, size_t ws_size,
                              hipStream_t stream){
  (void)in_sizes; (void)n_in; (void)out_size; (void)ws_size;
  float* ws=(float*)d_ws;
  const float* note    =(const float*)d_in[0];
  const float* pv      =(const float*)d_in[1];
  const float* res     =(const float*)d_in[2];
  const float* edges   =(const float*)d_in[3];
  const int*   bn      =(const int*)d_in[4];
  const float* w_style =(const float*)d_in[5];
  const float* b_style =(const float*)d_in[6];
  const float* w_init1 =(const float*)d_in[7];
  const float* b_init1 =(const float*)d_in[8];
  const float* w_init2 =(const float*)d_in[9];
  const float* b_init2 =(const float*)d_in[10];
  const float* gg_wa   =(const float*)d_in[11];
  const float* gg_ba   =(const float*)d_in[12];
  const float* gg_wz   =(const float*)d_in[13];
  const float* gg_wr   =(const float*)d_in[14];
  const float* gg_wh   =(const float*)d_in[15];
  const float* gg_uz   =(const float*)d_in[16];
  const float* gg_ur   =(const float*)d_in[17];
  const float* gg_uh   =(const float*)d_in[18];
  const float* abw     =(const float*)d_in[19];
  const float* abb     =(const float*)d_in[20];
  const float* abc     =(const float*)d_in[21];
  const float* amw     =(const float*)d_in[22];
  const float* amb     =(const float*)d_in[23];
  const float* amc     =(const float*)d_in[24];
  const float* wih0f   =(const float*)d_in[25];
  const float* whh0f   =(const float*)d_in[26];
  const float* b0f     =(const float*)d_in[27];
  const float* wih0b   =(const float*)d_in[28];
  const float* whh0b   =(const float*)d_in[29];
  const float* b0b     =(const float*)d_in[30];
  const float* wih1f   =(const float*)d_in[31];
  const float* whh1f   =(const float*)d_in[32];
  const float* b1f     =(const float*)d_in[33];
  const float* wih1b   =(const float*)d_in[34];
  const float* whh1b   =(const float*)d_in[35];
  const float* b1b     =(const float*)d_in[36];
  const float* w_tempo =(const float*)d_in[37];
  const float* b_tempo =(const float*)d_in[38];
  const float* w_fc1   =(const float*)d_in[39];
  const float* b_fc1   =(const float*)d_in[40];
  const float* w_fc2   =(const float*)d_in[41];
  const float* b_fc2   =(const float*)d_in[42];
  float* dout=(float*)d_out;

  hipMemsetAsync(ws+OFF_CUR, 0, NN*sizeof(int), stream);
  k_setup<<<NB_ADJ+NB_WA3+NB_INIT,128,0,stream>>>(
      gg_wa,gg_ba,gg_wz,gg_wr,gg_wh,
      note,pv,w_style,b_style,w_init1,b_init1,w_init2,b_init2,
      edges,ws,dout);

  for (int it=0; it<2; it++){
    k_mstat<<<dim3(200,12),64,0,stream>>>(ws);      // also emits M3(h0)
    k_agg_gru<<<NN,128,0,stream>>>(ws,gg_uz,gg_ur,gg_uh);          // g=0
    for (int g=1; g<3; g++){
      k_m3dyn<<<dim3(200,12),64,0,stream>>>(ws);
      k_agg_gru<<<NN,128,0,stream>>>(ws,gg_uz,gg_ur,gg_uh);
    }
    k_attn_xw<<<NBEAT,128,0,stream>>>(ws,amw,amb,amc,abw,abb,abc,res,
                                      wih0f,b0f,wih0b,b0b,ws+OFF_XW);
    k_scan<<<2,64,0,stream>>>(ws+OFF_XW,whh0f,whh0b,ws+OFF_RNN0);
    k_xw<<<2*NBEAT,128,0,stream>>>(ws+OFF_RNN0,64,wih1f,b1f,wih1b,b1b,ws+OFF_XW);
    k_scan<<<2,64,0,stream>>>(ws+OFF_XW,whh1f,whh1b,ws+OFF_RNN1);
    k_fc<<<NN,64,0,stream>>>(ws,bn,w_fc1,b_fc1,w_fc2,b_fc2,w_tempo,b_tempo,dout,it);
  }
}

// Round 16
// 906.055 us; speedup vs baseline: 3.3804x; 1.0150x over previous
//
#include <hip/hip_runtime.h>
#include <stdint.h>

// ---------------- problem constants ----------------
#define NN     1600
#define NBEAT  200
#define FINW   299
#define HSTR   300      // padded row stride for h
#define SECW   43
#define EDG    12
#define C3     129      // 3*43 projected width
#define CM     128      // main columns (129th handled separately)
#define DEG_CAP 256     // per-destination adjacency bucket (mean 77, max~112)

// fused-setup block ranges (all 192-thread blocks); adj FIRST so the memory-bound
// scan starts immediately and overlaps the compute-bound wa3/init blocks.
#define NB_ADJ  2560                  // 2560*192 = 491520 scan threads
#define NB_WA3  450                   // 8 rows/block: 450*8=3600 >= 3589 (3588 wa rows + ba)
#define NB_INIT NN                    // 1600

__device__ __forceinline__ float sigm(float x){ return 1.0f/(1.0f+__expf(-x)); }
__device__ __forceinline__ float tanh_(float x){ return 2.0f/(1.0f+__expf(-2.0f*x)) - 1.0f; }

// ---------------- workspace layout (4-byte words) ----------------
constexpr size_t OFF_H    = 0;                                   // 1600*300
constexpr size_t OFF_WA3  = OFF_H    + (size_t)NN*HSTR;          // 12*299*128
constexpr size_t OFF_WA3X = OFF_WA3  + (size_t)EDG*FINW*CM;      // 12*299
constexpr size_t OFF_B3   = OFF_WA3X + (size_t)EDG*FINW;         // 132
constexpr size_t OFF_MST  = OFF_B3   + 132;                      // 12*1600*128
constexpr size_t OFF_MSTX = OFF_MST  + (size_t)EDG*NN*CM;        // 12*1600
constexpr size_t OFF_M3   = OFF_MSTX + (size_t)EDG*NN;           // 12*1600*128
constexpr size_t OFF_M3X  = OFF_M3   + (size_t)EDG*NN*CM;        // 12*1600
constexpr size_t OFF_CUR  = OFF_M3X  + (size_t)EDG*NN;           // 1600 ints (degree counters)
constexpr size_t OFF_ADJR = OFF_CUR  + NN;                       // 1600*256 ints
constexpr size_t OFF_XW   = OFF_ADJR + (size_t)NN*DEG_CAP;       // 2*200*128
constexpr size_t OFF_RNN0 = OFF_XW   + (size_t)2*NBEAT*128;      // 200*64
constexpr size_t OFF_RNN1 = OFF_RNN0 + (size_t)NBEAT*64;         // 200*64

// ---------------- fused setup: adj | wa3(8-row GEMM) | init (one dispatch) ----------------
__global__ __launch_bounds__(192) void k_setup(
    const float* wa, const float* ba, const float* wz, const float* wr, const float* wh,
    const float* note, const float* pv, const float* w_style, const float* b_style,
    const float* w1, const float* b1, const float* w2, const float* b2,
    const float* edges, float* ws, float* dout){
  int blk = blockIdx.x;
  int t = threadIdx.x;
  if (blk < NB_ADJ){
    // ---- adj: sparse edge extraction into fixed-width buckets.
    // 4-deep load batching: 4 outstanding strided uint4 loads per thread per batch.
    int* cur  = (int*)(ws + OFF_CUR);
    int* adjr = (int*)(ws + OFF_ADJR);
    const uint4* p = (const uint4*)edges;
    const unsigned int nvec = 7680000u;   // 12*1600*1600/4
    const unsigned int stride = (unsigned int)NB_ADJ*192u;
    unsigned int v0 = (unsigned int)blk*192u + t;
    for (unsigned int b0 = v0; b0 < nvec; b0 += 4u*stride){
      unsigned int v1=b0+stride, v2=b0+2u*stride, v3=b0+3u*stride;
      bool g1=v1<nvec, g2=v2<nvec, g3=v3<nvec;
      uint4 w0 = p[b0];
      uint4 w1v = g1 ? p[v1] : make_uint4(0,0,0,0);
      uint4 w2v = g2 ? p[v2] : make_uint4(0,0,0,0);
      uint4 w3v = g3 ? p[v3] : make_uint4(0,0,0,0);
      uint4 wv[4] = {w0,w1v,w2v,w3v};
      unsigned int vv[4] = {b0,v1,v2,v3};
      #pragma unroll
      for (int u=0; u<4; u++){
        uint4 w = wv[u];
        if ((w.x|w.y|w.z|w.w)==0u) continue;
        unsigned int base = vv[u]*4u;
        unsigned int arr[4]={w.x,w.y,w.z,w.w};
        #pragma unroll
        for (int q=0;q<4;q++){
          if (arr[q]){
            unsigned int idx=base+q;
            unsigned int j=idx%1600u;
            int slot=atomicAdd(&cur[j],1);
            if (slot<DEG_CAP) adjr[j*DEG_CAP + slot]=(int)(idx/1600u);  // row = e*1600+i
          }
        }
      }
    }
  } else if (blk < NB_ADJ + NB_WA3){
    // ---- wa3 as blocked GEMM: 8 rows of [3588x299]@[299x129] per block.
    // A-rows staged transposed in LDS (lrow[s][8]); weight load amortized over 8 rows.
    int base = (blk - NB_ADJ)*8;   // row base in [0,3600); row 3588 = ba; 3589+ skipped
    __shared__ __align__(16) float lrow[299*8];
    for (int x=t; x<8*299; x+=192){
      int r = x & 7, s = x >> 3;
      int R = base + r;
      float v = 0.f;
      if (R < 3588)       v = wa[(size_t)R*FINW + s];
      else if (R == 3588) v = ba[s];
      lrow[s*8 + r] = v;
    }
    __syncthreads();
    if (t < C3){
      const float* Wp; int cc;
      if (t<43){Wp=wz; cc=t;} else if (t<86){Wp=wr; cc=t-43;} else {Wp=wh; cc=t-86;}
      float acc[8];
      #pragma unroll
      for (int r=0;r<8;r++) acc[r]=0.f;
      for (int s=0;s<FINW;s++){
        float w = Wp[s*43+cc];
        float4 lo = *(const float4*)&lrow[s*8];
        float4 hi = *(const float4*)&lrow[s*8+4];
        acc[0]+=lo.x*w; acc[1]+=lo.y*w; acc[2]+=lo.z*w; acc[3]+=lo.w*w;
        acc[4]+=hi.x*w; acc[5]+=hi.y*w; acc[6]+=hi.z*w; acc[7]+=hi.w*w;
      }
      #pragma unroll
      for (int r=0;r<8;r++){
        int R = base + r;
        if (R < 3588){
          if (t<CM) ws[OFF_WA3 + (size_t)R*CM + t] = acc[r];
          else      ws[OFF_WA3X + R]               = acc[r];
        } else if (R == 3588){
          ws[OFF_B3 + t] = acc[r];
        }
      }
    }
  } else {
    // ---- init: perf_z + init_out + assemble h row; writes total[0] ----
    int i = blk - NB_ADJ - NB_WA3;
    __shared__ float lnote[128];
    __shared__ float lh1[64];
    __shared__ float lo[11];
    __shared__ float lperf[64];
    if (t<128) lnote[t]=note[i*128+t];
    if (t>=64 && t<128){
      int u=t-64;
      float acc=b_style[u];
      for (int k=0;k<16;k++) acc += pv[k]*w_style[k*64+u];
      lperf[u]=fmaxf(acc,0.f);
    }
    __syncthreads();
    if (t<64){
      float acc=b1[t];
      for (int k=0;k<128;k++) acc += lnote[k]*w1[k*64+t];
      lh1[t]=fmaxf(acc,0.f);
    }
    __syncthreads();
    if (t<11){
      float acc=b2[t];
      for (int s=0;s<64;s++) acc += lh1[s]*w2[s*11+t];
      lo[t]=acc;
      dout[17600 + i*11 + t] = acc;
    }
    __syncthreads();
    for (int c=t;c<FINW;c+=192){
      float v;
      if (c<128)      v=lnote[c];
      else if (c<192) v=lperf[c-128];
      else if (c<256) v=0.f;
      else if (c<267) v=lo[c-256];
      else            v=0.f;
      ws[OFF_H + (size_t)i*HSTR + c]=v;
    }
  }
}

// ---------------- static message part + M3(h0) (once per seq-iter) ----------------
__global__ void k_mstat(float* ws){
  int e = blockIdx.y; int i0 = blockIdx.x*8;
  int t = threadIdx.x;
  __shared__ float lh[8][256];
  __shared__ float lh2[8][44];
  const float* h = ws + OFF_H;
  for (int x=t; x<512; x+=64){
    int r = x>>6, dq = x&63;
    ((float4*)&lh[r][0])[dq] = ((const float4*)(h + (size_t)(i0+r)*HSTR))[dq];
  }
  for (int x=t; x<88; x+=64){
    int r = x/11, dq = x-r*11;
    ((float4*)&lh2[r][0])[dq] = ((const float4*)(h + (size_t)(i0+r)*HSTR + 256))[dq];
  }
  __syncthreads();
  const float* wm = ws + OFF_WA3 + (size_t)e*FINW*CM;
  int c0 = 2*t;
  float acc[8][2];
  #pragma unroll
  for (int r=0;r<8;r++){acc[r][0]=0.f;acc[r][1]=0.f;}
  for (int d=0; d<256; d+=4){
    float4 hv[8];
    #pragma unroll
    for (int r=0;r<8;r++) hv[r] = *(const float4*)&lh[r][d];
    #pragma unroll
    for (int dd=0;dd<4;dd++){
      float2 w = *(const float2*)(wm + (size_t)(d+dd)*CM + c0);
      #pragma unroll
      for (int r=0;r<8;r++){
        float hvv = ((const float*)&hv[r])[dd];
        acc[r][0] += hvv*w.x; acc[r][1] += hvv*w.y;
      }
    }
  }
  float* mst = ws + OFF_MST + ((size_t)e*NN + i0)*CM;
  #pragma unroll
  for (int r=0;r<8;r++) *(float2*)(mst + (size_t)r*CM + c0) = make_float2(acc[r][0],acc[r][1]);
  // continue over dynamic cols 256..298 -> M3 = mst + hs@wd
  const float* wd = wm + (size_t)256*CM;
  for (int d=0; d<SECW; d++){
    float2 w = *(const float2*)(wd + (size_t)d*CM + c0);
    #pragma unroll
    for (int r=0;r<8;r++){
      float hvv = lh2[r][d];
      acc[r][0] += hvv*w.x; acc[r][1] += hvv*w.y;
    }
  }
  float* m3 = ws + OFF_M3 + ((size_t)e*NN + i0)*CM;
  #pragma unroll
  for (int r=0;r<8;r++) *(float2*)(m3 + (size_t)r*CM + c0) = make_float2(acc[r][0],acc[r][1]);
  if (t<8){
    const float* wx = ws + OFF_WA3X + (size_t)e*FINW;
    float a=0.f;
    for (int d=0; d<256; d++) a += lh[t][d]*wx[d];
    ws[OFF_MSTX + (size_t)e*NN + i0 + t] = a;
    for (int d=0; d<SECW; d++) a += lh2[t][d]*wx[256+d];
    ws[OFF_M3X + (size_t)e*NN + i0 + t] = a;
  }
}

// ---------------- M3 recompute (g>=1) ----------------
__global__ void k_m3dyn(float* ws){
  int e=blockIdx.y, i0=blockIdx.x*8, t=threadIdx.x;
  __shared__ float lhs[8][44];
  const float* h = ws + OFF_H;
  for (int x=t; x<8*43; x+=64){ int r=x/43, d=x-r*43; lhs[r][d]=h[(size_t)(i0+r)*HSTR+256+d]; }
  __syncthreads();
  const float* wd  = ws + OFF_WA3 + ((size_t)e*FINW+256)*CM;
  const float* mst = ws + OFF_MST + ((size_t)e*NN+i0)*CM;
  int c0=2*t;
  float acc[8][2];
  #pragma unroll
  for (int r=0;r<8;r++){ float2 m=*(const float2*)(mst+(size_t)r*CM+c0); acc[r][0]=m.x; acc[r][1]=m.y; }
  for (int d=0; d<43; d++){
    float2 w=*(const float2*)(wd + (size_t)d*CM + c0);
    #pragma unroll
    for (int r=0;r<8;r++){ float hv=lhs[r][d]; acc[r][0]+=hv*w.x; acc[r][1]+=hv*w.y; }
  }
  float* m3 = ws + OFF_M3 + ((size_t)e*NN+i0)*CM;
  #pragma unroll
  for (int r=0;r<8;r++) *(float2*)(m3+(size_t)r*CM+c0)=make_float2(acc[r][0],acc[r][1]);
  if (t<8){
    float a = ws[OFF_MSTX + (size_t)e*NN+i0+t];
    const float* wx = ws + OFF_WA3X + (size_t)e*FINW + 256;
    for (int d=0;d<43;d++) a += lhs[t][d]*wx[d];
    ws[OFF_M3X + (size_t)e*NN+i0+t]=a;
  }
}

// gather (LDS-staged adjacency + 8 independent accumulators) + GRU update
__global__ void k_agg_gru(float* ws, const float* uz, const float* ur, const float* uh){
  int j=blockIdx.x, t=threadIdx.x;   // 128 threads
  __shared__ float lpre[C3];
  __shared__ float lhs[SECW];
  __shared__ float lrh[SECW];
  __shared__ int   ladj[DEG_CAP];
  float* h = ws + OFF_H;
  const int* cur =(const int*)(ws+OFF_CUR);
  const int* adjr=(const int*)(ws+OFF_ADJR) + (size_t)j*DEG_CAP;
  int cnt = cur[j]; if (cnt>DEG_CAP) cnt=DEG_CAP;
  for (int k=t;k<cnt;k+=128) ladj[k]=adjr[k];
  if (t<SECW) lhs[t] = h[(size_t)j*HSTR + 256 + t];
  __syncthreads();
  const float* M3=ws+OFF_M3; const float* M3X=ws+OFF_M3X;
  float a0 = ws[OFF_B3 + t];
  float ax = (t==0)? ws[OFF_B3+128] : 0.f;
  float p1=0.f,p2=0.f,p3=0.f,p4=0.f,p5=0.f,p6=0.f,p7=0.f;
  int k=0;
  for (; k+8<=cnt; k+=8){
    int r0=ladj[k],r1=ladj[k+1],r2=ladj[k+2],r3=ladj[k+3];
    int r4=ladj[k+4],r5=ladj[k+5],r6=ladj[k+6],r7=ladj[k+7];
    a0 += M3[(size_t)r0*CM+t];
    p1 += M3[(size_t)r1*CM+t];
    p2 += M3[(size_t)r2*CM+t];
    p3 += M3[(size_t)r3*CM+t];
    p4 += M3[(size_t)r4*CM+t];
    p5 += M3[(size_t)r5*CM+t];
    p6 += M3[(size_t)r6*CM+t];
    p7 += M3[(size_t)r7*CM+t];
    if (t==0) ax += ((M3X[r0]+M3X[r1])+(M3X[r2]+M3X[r3]))
                  + ((M3X[r4]+M3X[r5])+(M3X[r6]+M3X[r7]));
  }
  for (; k<cnt; k++){ int r=ladj[k]; a0+=M3[(size_t)r*CM+t]; if(t==0) ax+=M3X[r]; }
  a0 += ((p1+p2)+(p3+p4)) + ((p5+p6)+p7);
  lpre[t]=a0; if (t==0) lpre[128]=ax;
  __syncthreads();
  float z=0.f;
  if (t<SECW){
    float az=lpre[t], ar=lpre[43+t];
    for (int d=0;d<SECW;d++){ float hv=lhs[d]; az+=hv*uz[d*43+t]; ar+=hv*ur[d*43+t]; }
    z=sigm(az);
    float r=sigm(ar);
    lrh[t]=r*lhs[t];
  }
  __syncthreads();
  if (t<SECW){
    float ah=lpre[86+t];
    for (int d=0;d<SECW;d++) ah += lrh[d]*uh[d*43+t];
    float cand=tanh_(ah);
    h[(size_t)j*HSTR+256+t] = (1.f-z)*lhs[t] + z*cand;
  }
}

// ---------------- beat attention + layer-0 LSTM input projection (fused) ----------------
__global__ void k_attn_xw(float* ws, const float* mw, const float* mb, const float* mc,
                          const float* bw, const float* bb, const float* bc,
                          const float* res,
                          const float* w0f, const float* bia0f,
                          const float* w0b, const float* bia0b, float* xw){
  int b=blockIdx.x, t=threadIdx.x;  // 128 threads
  float* h=ws+OFF_H;
  __shared__ float sm[8][8];
  __shared__ float wgt[8][8];
  __shared__ float sb[8];
  __shared__ float wb_[8];
  __shared__ float lb[52];
  int n=t>>3, hh=t&7;
  if (t<64){
    const float* mrow = h + (size_t)(b*8+n)*HSTR + 267;
    float sim=0.f;
    for (int d=0;d<4;d++){
      int c=hh*4+d;
      float acc=mb[c];
      for (int k=0;k<32;k++) acc += mrow[k]*mw[k*32+c];
      sim += tanh_(acc)*mc[c];
    }
    sm[n][hh]=sim;
  }
  if (t<8){
    const float* irow = h + (size_t)(b*8+t)*HSTR + 256;
    float sim=0.f;
    for (int d=0;d<11;d++){
      float acc=bb[d];
      for (int k=0;k<11;k++) acc += irow[k]*bw[k*11+d];
      sim += tanh_(acc)*bc[d];
    }
    sb[t]=sim;
  }
  __syncthreads();
  if (t<64){
    float m=-1e30f;
    for (int q=0;q<8;q++) m=fmaxf(m, sm[q][hh]);
    float Z=0.f;
    for (int q=0;q<8;q++) Z+=__expf(sm[q][hh]-m);
    wgt[n][hh]=__expf(sm[n][hh]-m)/Z;
  }
  if (t<8){
    float m=-1e30f;
    for (int q=0;q<8;q++) m=fmaxf(m, sb[q]);
    float Z=0.f;
    for (int q=0;q<8;q++) Z+=__expf(sb[q]-m);
    wb_[t]=__expf(sb[t]-m)/Z;
  }
  __syncthreads();
  if (t<32){
    int hh2=t>>2;
    float acc=0.f;
    for (int q=0;q<8;q++) acc += wgt[q][hh2]* h[(size_t)(b*8+q)*HSTR + 267 + t];
    lb[11+t]=acc;
  }
  if (t<11){
    float acc=0.f;
    for (int q=0;q<8;q++) acc += wb_[q]* h[(size_t)(b*8+q)*HSTR + 256 + t];
    lb[t]=acc;
  }
  if (t<8) lb[43+t]=res[b*8+t];
  __syncthreads();
  float acc0=bia0f[t], acc1=bia0b[t];
  for (int k=0;k<51;k++){
    float v=lb[k];
    acc0 += v*w0f[t*51+k];
    acc1 += v*w0b[t*51+k];
  }
  xw[((size_t)0*NBEAT + b)*128 + t]=acc0;
  xw[((size_t)1*NBEAT + b)*128 + t]=acc1;
}

// ---------------- LSTM layer-1 input projection ----------------
__global__ void k_xw(const float* inp, int din, const float* wf, const float* bf_,
                     const float* wb, const float* bb_, float* xw){
  int bid=blockIdx.x; int tt=bid>>1, dir=bid&1;
  const float* w = dir? wb:wf; const float* bia = dir? bb_:bf_;
  __shared__ float rowl[64];
  int t=threadIdx.x;   // 128 threads
  if (t<din) rowl[t]=inp[(size_t)tt*din+t];
  __syncthreads();
  float acc=bia[t];
  for (int k=0;k<din;k++) acc += rowl[k]*w[t*din+k];
  xw[((size_t)dir*NBEAT + tt)*128 + t]=acc;
}

// R5/R10 scan verbatim (PASSED @87us): one wave per direction; lane l<32: i_l,g_l; l>=32: f,o;
// c in high lanes. h via LDS (no inner wave_barriers!); x staged in 8-step LDS chunks.
#define CH 8
__global__ __launch_bounds__(64,1) void k_scan(const float* xw, const float* whh_f,
                                               const float* whh_b, float* out){
  int dir = blockIdx.x;
  int l = threadIdx.x;
  const float* whh = dir ? whh_b : whh_f;
  float4 rA[8], rB[8];
  #pragma unroll
  for (int q=0;q<8;q++){
    rA[q] = *(const float4*)&whh[l*32 + q*4];
    rB[q] = *(const float4*)&whh[(l+64)*32 + q*4];
  }
  __shared__ __align__(16) float xb[2][CH*128];
  __shared__ __align__(16) float lds_h[32];
  if (l<32) lds_h[l]=0.f;
  const float* x = xw + (size_t)dir*NBEAT*128;
  int half = l>>5, q4 = l&31;
  int stp = dir ? -1 : 1;
  float4 st[4];
  #pragma unroll
  for (int r=0;r<4;r++){
    int s = 2*r + half;
    int ti = dir ? (NBEAT-1-s) : s;
    st[r] = ((const float4*)&x[ti*128])[q4];
  }
  #pragma unroll
  for (int r=0;r<4;r++){ int u=2*r+half; ((float4*)&xb[0][u*128])[q4]=st[r]; }
  __builtin_amdgcn_wave_barrier();
  float creg = 0.f;
  int tt = dir ? NBEAT-1 : 0;
  for (int c=0;c<NBEAT/CH;c++){
    int buf = c&1;
    if (c+1 < NBEAT/CH){       // issue next chunk's global loads now (consumed at chunk end)
      #pragma unroll
      for (int r=0;r<4;r++){
        int s = (c+1)*CH + 2*r + half;
        int ti = dir ? (NBEAT-1-s) : s;
        st[r] = ((const float4*)&x[ti*128])[q4];
      }
    }
    #pragma unroll
    for (int u=0;u<CH;u++){
      float cxA = xb[buf][u*128 + l];
      float cxB = xb[buf][u*128 + 64 + l];
      float4 hv[8];
      #pragma unroll
      for (int q=0;q<8;q++) hv[q] = *(const float4*)&lds_h[q*4];   // broadcast reads
      float a[8], bq[8];
      #pragma unroll
      for (int q=0;q<8;q++){
        float4 h4=hv[q], wa=rA[q], wb=rB[q];
        a[q]  = h4.x*wa.x + h4.y*wa.y + h4.z*wa.z + h4.w*wa.w;
        bq[q] = h4.x*wb.x + h4.y*wb.y + h4.z*wb.z + h4.w*wb.w;
      }
      float accA = cxA + ((a[0]+a[1])+(a[2]+a[3])) + ((a[4]+a[5])+(a[6]+a[7]));
      float accB = cxB + ((bq[0]+bq[1])+(bq[2]+bq[3])) + ((bq[4]+bq[5])+(bq[6]+bq[7]));
      float pA  = sigm(accA);      // sigm(i) low lanes, sigm(f) high lanes
      float pBt = tanh_(accB);     // tanh(g) low lanes
      float pBs = sigm(accB);      // sigm(o) high lanes
      float prod = pA * pBt;
      float prodIn = __shfl(prod, l & 31, 64);
      creg = pA*creg + prodIn;     // c update (high lanes valid)
      float hnew = pBs * tanh_(creg);
      if (l>=32){
        lds_h[l&31] = hnew;        // program order + LDS aliasing keep write->read ordered in-wave
        out[(size_t)tt*64 + dir*32 + (l&31)] = hnew;
      }
      tt += stp;
    }
    if (c+1 < NBEAT/CH){
      #pragma unroll
      for (int r=0;r<4;r++){ int u=2*r+half; ((float4*)&xb[1-buf][u*128])[q4]=st[r]; }
      __builtin_amdgcn_wave_barrier();
    }
  }
}

// ---------------- fc head + final_out + h update (tempo fused) ----------------
__global__ void k_fc(float* ws, const int* bn, const float* w1, const float* b1,
                     const float* w2, const float* b2,
                     const float* wt, const float* bt, float* dout, int it){
  int i=blockIdx.x, t=threadIdx.x;   // 64 threads
  __shared__ float row[FINW];
  __shared__ float hid[32];
  __shared__ float fo[11];
  float* h=ws+OFF_H;
  int b = bn[i];
  const float* rnn = ws+OFF_RNN1;
  for (int c=t;c<FINW;c+=64){
    float v;
    if (c>=192 && c<256){ v=rnn[(size_t)b*64 + c-192]; h[(size_t)i*HSTR+c]=v; }
    else v=h[(size_t)i*HSTR+c];
    row[c]=v;
  }
  float tv = rnn[(size_t)b*64 + t]*wt[t];
  #pragma unroll
  for (int off=32; off; off>>=1) tv += __shfl_xor(tv, off, 64);
  __syncthreads();
  if (t<32){
    float acc=b1[t];
    for (int k=0;k<FINW;k++) acc += row[k]*w1[k*32+t];
    hid[t]=fmaxf(acc,0.f);
  }
  __syncthreads();
  if (t<10){
    float acc=b2[t];
    for (int m=0;m<32;m++) acc += hid[m]*w2[m*10+t];
    fo[1+t]=acc;
  }
  if (t==0) fo[0]=tv + bt[0];
  __syncthreads();
  if (t<11){
    float v=fo[t];
    h[(size_t)i*HSTR+256+t]=v;
    dout[(size_t)(2+it)*17600 + i*11 + t]=v;
    if (it==1) dout[i*11+t]=v;
  }
}

// ---------------- launcher ----------------
extern "C" void kernel_launch(void* const* d_in, const int* in_sizes, int n_in,
                              void* d_out, int out_size, void* d_ws, size_t ws_size,
                              hipStream_t stream){
  (void)in_sizes; (void)n_in; (void)out_size; (void)ws_size;
  float* ws=(float*)d_ws;
  const float* note    =(const float*)d_in[0];
  const float* pv      =(const float*)d_in[1];
  const float* res     =(const float*)d_in[2];
  const float* edges   =(const float*)d_in[3];
  const int*   bn      =(const int*)d_in[4];
  const float* w_style =(const float*)d_in[5];
  const float* b_style =(const float*)d_in[6];
  const float* w_init1 =(const float*)d_in[7];
  const float* b_init1 =(const float*)d_in[8];
  const float* w_init2 =(const float*)d_in[9];
  const float* b_init2 =(const float*)d_in[10];
  const float* gg_wa   =(const float*)d_in[11];
  const float* gg_ba   =(const float*)d_in[12];
  const float* gg_wz   =(const float*)d_in[13];
  const float* gg_wr   =(const float*)d_in[14];
  const float* gg_wh   =(const float*)d_in[15];
  const float* gg_uz   =(const float*)d_in[16];
  const float* gg_ur   =(const float*)d_in[17];
  const float* gg_uh   =(const float*)d_in[18];
  const float* abw     =(const float*)d_in[19];
  const float* abb     =(const float*)d_in[20];
  const float* abc     =(const float*)d_in[21];
  const float* amw     =(const float*)d_in[22];
  const float* amb     =(const float*)d_in[23];
  const float* amc     =(const float*)d_in[24];
  const float* wih0f   =(const float*)d_in[25];
  const float* whh0f   =(const float*)d_in[26];
  const float* b0f     =(const float*)d_in[27];
  const float* wih0b   =(const float*)d_in[28];
  const float* whh0b   =(const float*)d_in[29];
  const float* b0b     =(const float*)d_in[30];
  const float* wih1f   =(const float*)d_in[31];
  const float* whh1f   =(const float*)d_in[32];
  const float* b1f     =(const float*)d_in[33];
  const float* wih1b   =(const float*)d_in[34];
  const float* whh1b   =(const float*)d_in[35];
  const float* b1b     =(const float*)d_in[36];
  const float* w_tempo =(const float*)d_in[37];
  const float* b_tempo =(const float*)d_in[38];
  const float* w_fc1   =(const float*)d_in[39];
  const float* b_fc1   =(const float*)d_in[40];
  const float* w_fc2   =(const float*)d_in[41];
  const float* b_fc2   =(const float*)d_in[42];
  float* dout=(float*)d_out;

  hipMemsetAsync(ws+OFF_CUR, 0, NN*sizeof(int), stream);
  k_setup<<<NB_ADJ+NB_WA3+NB_INIT,192,0,stream>>>(
      gg_wa,gg_ba,gg_wz,gg_wr,gg_wh,
      note,pv,w_style,b_style,w_init1,b_init1,w_init2,b_init2,
      edges,ws,dout);

  for (int it=0; it<2; it++){
    k_mstat<<<dim3(200,12),64,0,stream>>>(ws);      // also emits M3(h0)
    k_agg_gru<<<NN,128,0,stream>>>(ws,gg_uz,gg_ur,gg_uh);          // g=0
    for (int g=1; g<3; g++){
      k_m3dyn<<<dim3(200,12),64,0,stream>>>(ws);
      k_agg_gru<<<NN,128,0,stream>>>(ws,gg_uz,gg_ur,gg_uh);
    }
    k_attn_xw<<<NBEAT,128,0,stream>>>(ws,amw,amb,amc,abw,abb,abc,res,
                                      wih0f,b0f,wih0b,b0b,ws+OFF_XW);
    k_scan<<<2,64,0,stream>>>(ws+OFF_XW,whh0f,whh0b,ws+OFF_RNN0);
    k_xw<<<2*NBEAT,128,0,stream>>>(ws+OFF_RNN0,64,wih1f,b1f,wih1b,b1b,ws+OFF_XW);
    k_scan<<<2,64,0,stream>>>(ws+OFF_XW,whh1f,whh1b,ws+OFF_RNN1);
    k_fc<<<NN,64,0,stream>>>(ws,bn,w_fc1,b_fc1,w_fc2,b_fc2,w_tempo,b_tempo,dout,it);
  }
}